// Round 16
// baseline (626.538 us; speedup 1.0000x reference)
//
#include <hip/hip_runtime.h>
#include <math.h>

#define DI static __device__ __forceinline__

DI float eluf(float x){ return x > 0.f ? x : expm1f(x); }
DI float lreluf(float x){ return x > 0.f ? x : 0.2f*x; }
DI float sigmf(float x){ return 1.f/(1.f+expf(-x)); }

constexpr int N=200, E=3200, HID=64, NH=16, OUTD=128, CAT=2048, SEQD=2240;

// ---- per-graph f32 scratch offsets (in floats) ----
constexpr int OH0   = 0;
constexpr int OWH   = OH0 + N*HID;
constexpr int OASN  = OWH + NH*N*OUTD;
constexpr int OADN  = OASN + NH*N;
constexpr int OH1   = OADN + NH*N;
constexpr int OXW1  = OH1 + N*CAT;
constexpr int OXW2  = OXW1 + 256;
constexpr int OEW1  = OXW2 + 256;
constexpr int OS1   = OEW1 + E;
constexpr int ODEG1 = OS1 + E;
constexpr int OSS1  = ODEG1 + 256;   // = ODEG1+256 (inline ns relies on this)
constexpr int ORAW1 = OSS1 + 256;
constexpr int OWH2  = ORAW1 + 256;
constexpr int OAS2  = OWH2 + N*OUTD;
constexpr int OAD2  = OAS2 + 256;
constexpr int OEWV  = OAD2 + 256;
constexpr int OH2B  = OEWV + E;
constexpr int OXS2  = OH2B + N*OUTD;
constexpr int OXD2  = OXS2 + 256;
constexpr int ODEG2 = OXD2 + 256;
constexpr int OSS2  = ODEG2 + 256;   // = ODEG2+256
constexpr int ORAW2 = OSS2 + 256;
constexpr int ORAW3 = ORAW2 + 256;
constexpr int PGF   = ORAW3 + 256;
constexpr int GLOBF = 10624;
constexpr int TOTF  = GLOBF + 2*PGF;

// ---- static device scratch ----
__device__ float G_F[TOTF];
__device__ float G_E2PART[(size_t)NH*2*E*OUTD];
__device__ float G_EDOTH[2*NH*E];
__device__ float G_WHHT[2*2*128*512];
__device__ int   G_PIDX[2*N*N];

DI float* gf(int g){ return G_F + GLOBF + (size_t)g*PGF; }
DI float* gwe_ae(){ return G_F; }
DI float* gv_e(){ return G_F + 1024; }
DI float* gxseq(){ return G_F + 4096; }
DI float* gxg(){ return G_F + 8576; }
DI int*   gpidx(int g){ return G_PIDX + g*N*N; }

struct GraphIn {
  const float *feat, *eattr, *adj, *n2n;
  const int   *eidx;
};

struct Params {
  GraphIn g[2];
  const float *W_h, *W_gat, *a_src, *a_dst, *a_e, *We_gat;
  const float *W_out, *ao_src, *ao_dst, *ao_e, *We_out;
  const float *ep1_w, *ep1_b, *ep2_w, *ep2_b;
  const float *g1_w, *g1_b, *g2_w, *g2_b, *g3_w, *g3_b;
  const float *Wih0, *Whh0, *b0, *Wih1, *Whh1, *b1, *fc_w, *fc_b;
  float *out;
};

// ---- fused init: zero atomic targets, pidx=-1, Whh transpose, precontract, h0+g1dot ----
constexpr int ZPG  = 2*E + 1024;              // per-graph floats to zero
constexpr int IB_Z = (2*ZPG+255)/256;         // 58
constexpr int IB_C = (2*N*N+255)/256;         // 313
constexpr int IB_D = (2*2*512*128)/256;       // 512
constexpr int IB_E = (NH*HID+CAT+3)/4;        // 768
constexpr int IB_H = (2*N+3)/4;               // 100 (4 node-units of 64 thr)
__global__ void k_init(Params P){
  int b = blockIdx.x, tid = threadIdx.x;
  if (b < IB_Z){
    int i = b*256 + tid;
    if (i < 2*ZPG){
      int g = i/ZPG, r = i%ZPG;
      int addr = r<E ? OEW1+r : (r<2*E ? OEWV+(r-E) :
                 (r<2*E+512 ? ODEG1+(r-2*E) : ODEG2+(r-2*E-512)));
      gf(g)[addr] = 0.f;
    }
  } else if (b < IB_Z+IB_C){
    int i = (b-IB_Z)*256 + tid; if (i < 2*N*N) G_PIDX[i] = -1;
  } else if (b < IB_Z+IB_C+IB_D){
    int idx = (b-IB_Z-IB_C)*256 + tid;
    int l = idx >> 17;
    int r = idx & 131071;
    int d = r >> 16;
    int r2 = r & 65535;
    int gate = r2 & 511;
    int k = r2 >> 9;
    const float* Whh = l ? P.Whh1 : P.Whh0;
    G_WHHT[idx] = Whh[((size_t)d*512+gate)*128 + k];
  } else if (b < IB_Z+IB_C+IB_D+IB_E){
    int gid = (b-IB_Z-IB_C-IB_D)*4 + (tid>>6);
    int lane = tid & 63;
    if (gid < NH*HID){
      int h = gid/HID, c = gid%HID;
      const float* W = P.We_gat + (size_t)(h*HID+c)*OUTD;
      const float* a = P.a_e + h*OUTD;
      float acc = 0.f;
      for (int o=lane;o<OUTD;o+=64) acc += W[o]*a[o];
      for (int off=32;off>0;off>>=1) acc += __shfl_down(acc,off);
      if (lane==0) gwe_ae()[gid] = acc;
    } else if (gid < NH*HID+CAT){
      int c = gid - NH*HID;
      const float* W = P.We_out + (size_t)c*OUTD;
      float acc = 0.f;
      for (int o=lane;o<OUTD;o+=64) acc += W[o]*P.ao_e[o];
      for (int off=32;off>0;off>>=1) acc += __shfl_down(acc,off);
      if (lane==0) gv_e()[c] = acc;
    }
  } else {
    // h0 = elu(feat@W_h) + fused g1 raw dot; one 64-lane wave per (n,g)
    int unit = (b-IB_Z-IB_C-IB_D-IB_E)*4 + (tid>>6);
    if (unit >= 2*N) return;
    int g = unit / N, n = unit % N, c = tid & 63;
    const float* feat = P.g[g].feat;
    float acc = 0.f;
    for (int k=0;k<HID;k++) acc += feat[n*HID+k]*P.W_h[k*HID+c];
    float v = eluf(acc);
    float* f = gf(g);
    f[OH0 + n*HID + c] = v;
    float r = v*P.g1_w[c];
    for (int off=32;off>0;off>>=1) r += __shfl_down(r,off);
    if (c==0) f[ORAW1+n] = r;
  }
}

// ---- Wh[h] = h0 @ W_gat[h] + fused asn/adn; y==NH slice does gpool1 output ----
__global__ void k_Wh(Params P){
  int n = blockIdx.x, h = blockIdx.y, g = blockIdx.z, o = threadIdx.x;
  float* f = gf(g);
  if (h == NH){
    if (n != 0) return;
    // gpool1: D=HID, no scale, raw=ORAW1, out offset 0 (128 threads)
    __shared__ float att[N];
    __shared__ float sb[128];
    for (int j = o; j < N; j += 128) att[j] = sigmf(f[ORAW1+j] + P.g1_b[0]);
    __syncthreads();
    float m = -3e38f;
    for (int j = o; j < N; j += 128) m = fmaxf(m, att[j]);
    sb[o] = m; __syncthreads();
    for (int s=64;s>0;s>>=1){ if (o<s) sb[o]=fmaxf(sb[o],sb[o+s]); __syncthreads(); }
    m = sb[0]; __syncthreads();
    float ss = 0.f;
    for (int j = o; j < N; j += 128){ float e = expf(att[j]-m); ss += e; }
    sb[o] = ss; __syncthreads();
    for (int s=64;s>0;s>>=1){ if (o<s) sb[o]+=sb[o+s]; __syncthreads(); }
    float inv = 1.f/sb[0]; __syncthreads();
    for (int j = o; j < N; j += 128) att[j] = expf(att[j]-m)*inv;
    __syncthreads();
    if (o < HID){
      float acc = 0.f;
      for (int j=0;j<N;j++) acc += att[j]*f[OH0 + j*HID + o];
      gxseq()[g*SEQD + o] = acc;
    }
    return;
  }
  __shared__ float hs[HID];
  __shared__ float sred[128], dred[128];
  if (o < HID) hs[o] = f[OH0 + n*HID + o];
  __syncthreads();
  const float* W = P.W_gat + (size_t)h*HID*OUTD + o;
  float acc = 0.f;
  for (int c=0;c<HID;c++) acc += hs[c]*W[(size_t)c*OUTD];
  f[OWH + ((size_t)h*N + n)*OUTD + o] = acc;
  sred[o] = acc*P.a_src[h*OUTD+o];
  dred[o] = acc*P.a_dst[h*OUTD+o];
  __syncthreads();
  for (int s=64;s>0;s>>=1){ if (o<s){ sred[o]+=sred[o+s]; dred[o]+=dred[o+s]; } __syncthreads(); }
  if (o==0){ f[OASN+h*N+n]=sred[0]; f[OADN+h*N+n]=dred[0]; }
}

// ---- GAT layer 1: 4 nodes/block ----
__global__ void k_att1(Params P){
  int nb = blockIdx.x, h = blockIdx.y, g = blockIdx.z, tid = threadIdx.x;
  int n0 = nb*4;
  __shared__ float z[4][N];
  __shared__ float red[128];
  __shared__ float sinv[4];
  float* f = gf(g);
  const float* adj = P.g[g].adj;
  const int* pidx = gpidx(g);
  const float* edoth = G_EDOTH + ((size_t)g*NH + h)*E;
  const float* adn = f + OADN + h*N;
  for (int i=0;i<4;i++){
    float asn = f[OASN + h*N + n0+i];
    for (int j = tid; j < N; j += 128){
      float a = adj[(n0+i)*N + j];
      float zz;
      if (a > 0.f){
        int p = pidx[(n0+i)*N + j];
        float ee = (p >= 0) ? edoth[p] : 0.f;
        zz = lreluf(asn + adn[j] + ee);
      } else zz = -1e9f;
      z[i][j] = zz;
    }
  }
  __syncthreads();
  for (int i=0;i<4;i++){
    float m = -3e38f;
    for (int j = tid; j < N; j += 128) m = fmaxf(m, z[i][j]);
    red[tid] = m; __syncthreads();
    for (int s=64;s>0;s>>=1){ if (tid<s) red[tid]=fmaxf(red[tid],red[tid+s]); __syncthreads(); }
    m = red[0]; __syncthreads();
    float ssum = 0.f;
    for (int j = tid; j < N; j += 128){ float e = expf(z[i][j]-m); z[i][j]=e; ssum += e; }
    red[tid] = ssum; __syncthreads();
    for (int s=64;s>0;s>>=1){ if (tid<s) red[tid]+=red[tid+s]; __syncthreads(); }
    if (tid==0) sinv[i] = 1.f/red[0];
    __syncthreads();
  }
  const float* wh = f + OWH + (size_t)h*N*OUTD;
  float a0=0.f,a1=0.f,a2=0.f,a3=0.f;
  for (int j=0;j<N;j++){
    float w = wh[(size_t)j*OUTD + tid];
    a0 += z[0][j]*w; a1 += z[1][j]*w; a2 += z[2][j]*w; a3 += z[3][j]*w;
  }
  f[OH1 + (size_t)(n0+0)*CAT + h*OUTD + tid] = eluf(a0*sinv[0]);
  f[OH1 + (size_t)(n0+1)*CAT + h*OUTD + tid] = eluf(a1*sinv[1]);
  f[OH1 + (size_t)(n0+2)*CAT + h*OUTD + tid] = eluf(a2*sinv[2]);
  f[OH1 + (size_t)(n0+3)*CAT + h*OUTD + tid] = eluf(a3*sinv[3]);
}

// ---- pool1 node dots + fused g2 raw gate dot ----
__global__ void k_xw1(Params P){
  int n = blockIdx.x, g = blockIdx.y, tid = threadIdx.x;
  __shared__ float s1b[256], s2b[256], s3b[256];
  float* f = gf(g);
  const float* x = f + OH1 + (size_t)n*CAT;
  float a1 = 0.f, a2 = 0.f, a3 = 0.f;
  for (int c = tid; c < CAT; c += 256){
    float xv = x[c];
    a1 += xv*P.ep1_w[c];
    a2 += xv*P.ep1_w[CAT+c];
    a3 += xv*P.g2_w[c];
  }
  s1b[tid]=a1; s2b[tid]=a2; s3b[tid]=a3; __syncthreads();
  for (int s=128;s>0;s>>=1){
    if (tid<s){ s1b[tid]+=s1b[tid+s]; s2b[tid]+=s2b[tid+s]; s3b[tid]+=s3b[tid+s]; }
    __syncthreads();
  }
  if (tid==0){ f[OXW1+n]=s1b[0]; f[OXW2+n]=s2b[0]; f[ORAW2+n]=s3b[0]; }
}

// ---------------- pool1 edge scores + segment sums ----------------
__global__ void k_s1(Params P){
  int e = blockIdx.x*256 + threadIdx.x, g = blockIdx.y;
  if (e >= E) return;
  float* f = gf(g);
  const int* ei = P.g[g].eidx;
  int s = ei[e], d = ei[E+e];
  float v = sigmf(f[OXW1+s] + f[OXW2+d] + f[OEW1+e] + P.ep1_b[0]);
  f[OS1+e] = v;
  atomicAdd(&f[OSS1+s], v);
  atomicAdd(&f[ODEG1+s], 1.f);
}

// ---------------- pairIdx: last edge wins ----------------
__global__ void k_pairs(Params P){
  int e = blockIdx.x*256 + threadIdx.x, g = blockIdx.y;
  if (e >= E) return;
  const int* ei = P.g[g].eidx;
  atomicMax(&gpidx(g)[ei[e]*N + ei[E+e]], e);
}

// ---- gpool output (pools 2/3): inline gate; column-tiled ----
__global__ void k_gpool_out(Params P, int xoff, int D, int odeg, int rawoff,
                            const float* b, int outoff){
  int cb = blockIdx.x, g = blockIdx.y, tid = threadIdx.x;
  __shared__ float att[N];
  __shared__ float sb[256];
  float* f = gf(g);
  for (int n = tid; n < N; n += 256){
    float sc = f[odeg+256+n]/(f[odeg+n]+1e-6f);
    att[n] = sigmf(f[rawoff+n]*sc + b[0]);
  }
  __syncthreads();
  float m = -3e38f;
  for (int n = tid; n < N; n += 256) m = fmaxf(m, att[n]);
  sb[tid] = m; __syncthreads();
  for (int s=128;s>0;s>>=1){ if (tid<s) sb[tid]=fmaxf(sb[tid],sb[tid+s]); __syncthreads(); }
  m = sb[0]; __syncthreads();
  float ss = 0.f;
  for (int n = tid; n < N; n += 256){ float e = expf(att[n]-m); ss += e; }
  sb[tid] = ss; __syncthreads();
  for (int s=128;s>0;s>>=1){ if (tid<s) sb[tid]+=sb[tid+s]; __syncthreads(); }
  float inv = 1.f/sb[0]; __syncthreads();
  for (int n = tid; n < N; n += 256){
    float sc = f[odeg+256+n]/(f[odeg+n]+1e-6f);
    att[n] = expf(att[n]-m)*inv*sc;
  }
  __syncthreads();
  int c = cb*256 + tid;
  if (c < D){
    const float* x = f + xoff;
    float acc = 0.f;
    for (int n=0;n<N;n++) acc += att[n]*x[(size_t)n*D + c];
    gxseq()[g*SEQD + outoff + c] = acc;
  }
}

// ---- Wh2 (N,2; 512 thr) + fused asad2 tail ----
__global__ void k_Wh2(Params P){
  int n = blockIdx.x, g = blockIdx.y, tid = threadIdx.x;
  int kq = tid >> 7, o = tid & 127;
  __shared__ float hrow[4][128];
  __shared__ float part[4][128];
  __shared__ float sr[128], dr[128];
  float* f = gf(g);
  const float* x = f + OH1 + (size_t)n*CAT;
  float acc = 0.f;
  for (int cc=0; cc<4; cc++){
    int c0 = kq*512 + cc*128;
    __syncthreads();
    hrow[kq][o] = x[c0 + o];
    __syncthreads();
    const float* W = P.W_out + (size_t)c0*OUTD + o;
    for (int j=0;j<128;j++) acc += hrow[kq][j]*W[(size_t)j*OUTD];
  }
  part[kq][o] = acc;
  __syncthreads();
  if (kq==0){
    float ns = f[OSS1+n]/(f[ODEG1+n]+1e-6f);
    float a = part[0][o]+part[1][o]+part[2][o]+part[3][o];
    float v = a*ns;
    f[OWH2 + (size_t)n*OUTD + o] = v;
    sr[o] = v*P.ao_src[o];
    dr[o] = v*P.ao_dst[o];
  }
  __syncthreads();
  for (int s=64;s>0;s>>=1){
    if (tid<s){ sr[tid]+=sr[tid+s]; dr[tid]+=dr[tid+s]; }
    __syncthreads();
  }
  if (tid==0){ f[OAS2+n]=sr[0]; f[OAD2+n]=dr[0]; }
}

// ---- GAT layer 2; fused xs2/xd2 + g3 raw gate dot ----
__global__ void k_att2(Params P){
  int n = blockIdx.x, g = blockIdx.y, tid = threadIdx.x;
  __shared__ float z[N];
  __shared__ float red[128];
  __shared__ float dred[128];
  __shared__ float gred[128];
  float* f = gf(g);
  const float* adj = P.g[g].adj;
  const int* pidx = gpidx(g);
  float asn = f[OAS2+n];
  const float* adn = f + OAD2;
  for (int j = tid; j < N; j += 128){
    float a = adj[n*N + j];
    float zz;
    if (a > 0.f){
      int p = pidx[n*N + j];
      float ee = (p >= 0) ? f[OEWV+p]*f[OS1+p] : 0.f;
      zz = lreluf(asn + adn[j] + ee);
    } else zz = -1e9f;
    z[j] = zz;
  }
  __syncthreads();
  float m = -3e38f;
  for (int j = tid; j < N; j += 128) m = fmaxf(m, z[j]);
  red[tid] = m; __syncthreads();
  for (int s=64;s>0;s>>=1){ if (tid<s) red[tid]=fmaxf(red[tid],red[tid+s]); __syncthreads(); }
  m = red[0]; __syncthreads();
  float ssum = 0.f;
  for (int j = tid; j < N; j += 128){ float e = expf(z[j]-m); z[j]=e; ssum += e; }
  red[tid] = ssum; __syncthreads();
  for (int s=64;s>0;s>>=1){ if (tid<s) red[tid]+=red[tid+s]; __syncthreads(); }
  float inv = 1.f/red[0]; __syncthreads();
  const float* wh = f + OWH2;
  float acc = 0.f;
  for (int j=0;j<N;j++){
    float w = z[j];
    if (w != 0.f) acc += w * wh[(size_t)j*OUTD + tid];
  }
  float v = acc*inv;
  f[OH2B + (size_t)n*OUTD + tid] = v;
  red[tid]  = v*P.ep2_w[tid];
  dred[tid] = v*P.ep2_w[OUTD+tid];
  gred[tid] = v*P.g3_w[tid];
  __syncthreads();
  for (int s=64;s>0;s>>=1){
    if (tid<s){ red[tid]+=red[tid+s]; dred[tid]+=dred[tid+s]; gred[tid]+=gred[tid+s]; }
    __syncthreads();
  }
  if (tid==0){ f[OXS2+n]=red[0]; f[OXD2+n]=dred[0]; f[ORAW3+n]=gred[0]; }
}

// ---- e2 partial: register-tiled 4x4, fused ew1/ewv + EDOTH ----
constexpr int TE2 = 16;
__global__ __launch_bounds__(128, 2) void k_e2p(Params P){
  int e0 = blockIdx.x*TE2, h = blockIdx.y, g = blockIdx.z, tid = threadIdx.x;
  int cg = tid & 31, eg = tid >> 5;
  int c4 = cg*4, e4 = eg*4;
  __shared__ float es_t[HID][TE2+1];
  __shared__ float tcol_t[OUTD][TE2];
  const float* __restrict__ ea = P.g[g].eattr + (size_t)e0*HID;
  for (int i = tid; i < TE2*HID; i += 128) es_t[i & 63][i >> 6] = ea[i];
  __syncthreads();
  const float* __restrict__ W1 = P.We_gat + (size_t)h*HID*OUTD;
  const float* __restrict__ weae = gwe_ae() + h*HID;
  float t[4][4];
  float ed[4] = {0.f,0.f,0.f,0.f};
  #pragma unroll
  for (int i=0;i<4;i++){ t[i][0]=0.f; t[i][1]=0.f; t[i][2]=0.f; t[i][3]=0.f; }
  for (int c=0;c<HID;c++){
    float ev0 = es_t[c][e4+0], ev1 = es_t[c][e4+1], ev2 = es_t[c][e4+2], ev3 = es_t[c][e4+3];
    float4 w  = *(const float4*)&W1[(size_t)c*OUTD + c4];
    t[0][0]+=ev0*w.x; t[0][1]+=ev0*w.y; t[0][2]+=ev0*w.z; t[0][3]+=ev0*w.w;
    t[1][0]+=ev1*w.x; t[1][1]+=ev1*w.y; t[1][2]+=ev1*w.z; t[1][3]+=ev1*w.w;
    t[2][0]+=ev2*w.x; t[2][1]+=ev2*w.y; t[2][2]+=ev2*w.z; t[2][3]+=ev2*w.w;
    t[3][0]+=ev3*w.x; t[3][1]+=ev3*w.y; t[3][2]+=ev3*w.z; t[3][3]+=ev3*w.w;
    float wc = weae[c];
    ed[0]+=ev0*wc; ed[1]+=ev1*wc; ed[2]+=ev2*wc; ed[3]+=ev3*wc;
  }
  if (cg==0){
    float* eo = G_EDOTH + ((size_t)g*NH+h)*E + e0 + e4;
    eo[0]=ed[0]; eo[1]=ed[1]; eo[2]=ed[2]; eo[3]=ed[3];
  }
  #pragma unroll
  for (int i=0;i<4;i++){
    t[i][0]=eluf(t[i][0]); t[i][1]=eluf(t[i][1]); t[i][2]=eluf(t[i][2]); t[i][3]=eluf(t[i][3]);
  }
  {
    float4 w1 = *(const float4*)&P.ep1_w[2*CAT + h*OUTD + c4];
    float4 wv = *(const float4*)&gv_e()[h*OUTD + c4];
    #pragma unroll
    for (int i=0;i<4;i++){
      float a1 = t[i][0]*w1.x + t[i][1]*w1.y + t[i][2]*w1.z + t[i][3]*w1.w;
      float a2 = t[i][0]*wv.x + t[i][1]*wv.y + t[i][2]*wv.z + t[i][3]*wv.w;
      for (int off=16;off>0;off>>=1){
        a1 += __shfl_down(a1,off,32);
        a2 += __shfl_down(a2,off,32);
      }
      if (cg==0){
        atomicAdd(&gf(g)[OEW1 + e0+e4+i], a1);
        atomicAdd(&gf(g)[OEWV + e0+e4+i], a2);
      }
    }
  }
  #pragma unroll
  for (int j=0;j<4;j++){
    int o = c4 + j;
    int slot = (eg + (o>>2)) & 3;
    float4 v; v.x=t[0][j]; v.y=t[1][j]; v.z=t[2][j]; v.w=t[3][j];
    *(float4*)&tcol_t[o][4*slot] = v;
  }
  __syncthreads();
  const float* __restrict__ W2 = P.We_out + (size_t)h*OUTD*OUTD;
  float acc[4][4];
  #pragma unroll
  for (int i=0;i<4;i++){ acc[i][0]=0.f; acc[i][1]=0.f; acc[i][2]=0.f; acc[i][3]=0.f; }
  #pragma unroll 4
  for (int o=0;o<OUTD;o++){
    int slot = (eg + (o>>2)) & 3;
    float4 tv = *(const float4*)&tcol_t[o][4*slot];
    float4 w  = *(const float4*)&W2[(size_t)o*OUTD + c4];
    acc[0][0]+=tv.x*w.x; acc[0][1]+=tv.x*w.y; acc[0][2]+=tv.x*w.z; acc[0][3]+=tv.x*w.w;
    acc[1][0]+=tv.y*w.x; acc[1][1]+=tv.y*w.y; acc[1][2]+=tv.y*w.z; acc[1][3]+=tv.y*w.w;
    acc[2][0]+=tv.z*w.x; acc[2][1]+=tv.z*w.y; acc[2][2]+=tv.z*w.z; acc[2][3]+=tv.z*w.w;
    acc[3][0]+=tv.w*w.x; acc[3][1]+=tv.w*w.y; acc[3][2]+=tv.w*w.z; acc[3][3]+=tv.w*w.w;
  }
  float* dst = G_E2PART + (((size_t)h*2 + g)*E + e0)*OUTD;
  #pragma unroll
  for (int i=0;i<4;i++){
    float4 v; v.x=acc[i][0]; v.y=acc[i][1]; v.z=acc[i][2]; v.w=acc[i][3];
    *(float4*)&dst[(size_t)(e4+i)*OUTD + c4] = v;
  }
}

// ---- finish: sum head-partials, elu, dot ep2_w; fused s2 scoring + segment sums ----
__global__ void k_ew2fin(Params P){
  int e0 = blockIdx.x*TE2, g = blockIdx.y, tid = threadIdx.x;
  __shared__ float lred[2][TE2];
  float* f = gf(g);
  float w2 = P.ep2_w[2*OUTD + tid];
  int lane = tid & 63, wvi = tid >> 6;
  for (int e=0;e<TE2;e++){
    const float* src = G_E2PART + ((size_t)g*E + e0 + e)*OUTD + tid;
    float a = 0.f;
    for (int h=0;h<NH;h++) a += src[(size_t)h*2*E*OUTD];
    float v = eluf(f[OS1+e0+e]*a) * w2;
    for (int off=32;off>0;off>>=1) v += __shfl_down(v,off);
    if (lane==0) lred[wvi][e]=v;
  }
  __syncthreads();
  if (tid < TE2){
    int e = e0 + tid;
    float ew2 = lred[0][tid]+lred[1][tid];
    const int* ei = P.g[g].eidx;
    int s = ei[e], d = ei[E+e];
    float v = sigmf(f[OXS2+s] + f[OXD2+d] + ew2 + P.ep2_b[0]);
    atomicAdd(&f[OSS2+s], v);
    atomicAdd(&f[ODEG2+s], 1.f);
  }
}

// ---- LSTM input projection (layer 0 only) ----
__global__ void k_lstm_xg(Params P){
  int gid = blockIdx.x*4 + (threadIdx.x>>6);
  int lane = threadIdx.x & 63;
  int t = gid >> 10;
  int rem = gid & 1023;
  int d = rem >> 9;
  int gate = rem & 511;
  const float* x = gxseq() + t*SEQD;
  const float* Wr = P.Wih0 + ((size_t)d*512 + gate)*SEQD;
  float acc = 0.f;
  for (int k=lane; k<SEQD; k+=64) acc += x[k]*Wr[k];
  for (int off=32; off>0; off>>=1) acc += __shfl_down(acc, off);
  if (lane==0) gxg()[(t*2 + d)*512 + gate] = acc + P.b0[d*512 + gate];
}

// ---- mega: rec0 + xg1 + rec1 + final in one block (1024 thr) ----
__global__ void k_mega(Params P){
  int tid = threadIdx.x;
  __shared__ float h[2][128], c[2][128], gbuf[2][512];
  __shared__ float y0l[2][256], xg1l[2][1024], y1last[256];
  __shared__ float sb[256], sb2[256];
  if (tid < 256){ int d=tid>>7, i=tid&127; h[d][i]=0.f; c[d][i]=0.f; }
  __syncthreads();
  // rec layer 0
  for (int s=0;s<2;s++){
    int d = tid>>9, gate = tid&511;
    int t = (d==0)? s : 1-s;
    float acc = gxg()[(t*2+d)*512+gate];
    const float* T = G_WHHT + (size_t)d*128*512;
    for (int k=0;k<128;k++) acc += h[d][k]*T[(size_t)k*512+gate];
    gbuf[d][gate] = acc;
    __syncthreads();
    if (tid < 256){
      int d2 = tid>>7, i = tid&127;
      int t2 = (d2==0)? s : 1-s;
      float ii = sigmf(gbuf[d2][i]);
      float ff = sigmf(gbuf[d2][128+i]);
      float gg = tanhf(gbuf[d2][256+i]);
      float oo = sigmf(gbuf[d2][384+i]);
      float cn = ff*c[d2][i] + ii*gg;
      c[d2][i] = cn;
      float hn = oo*tanhf(cn);
      h[d2][i] = hn;
      y0l[t2][d2*128+i] = hn;
    }
    __syncthreads();
  }
  // xg layer 1: wave-per-dot, 2048 dots over 16 waves
  {
    int wave = tid>>6, lane = tid&63;
    for (int dot = wave; dot < 2048; dot += 16){
      int t = dot>>10, rem = dot&1023;
      int d = rem>>9, gate = rem&511;
      const float* Wr = P.Wih1 + ((size_t)d*512+gate)*256;
      float acc = 0.f;
      for (int k=lane;k<256;k+=64) acc += y0l[t][k]*Wr[k];
      for (int off=32;off>0;off>>=1) acc += __shfl_down(acc,off);
      if (lane==0) xg1l[t][rem] = acc + P.b1[d*512+gate];
    }
  }
  __syncthreads();
  if (tid < 256){ int d=tid>>7, i=tid&127; h[d][i]=0.f; c[d][i]=0.f; }
  __syncthreads();
  // rec layer 1 (capture t==1 output)
  for (int s=0;s<2;s++){
    int d = tid>>9, gate = tid&511;
    int t = (d==0)? s : 1-s;
    float acc = xg1l[t][d*512+gate];
    const float* T = G_WHHT + (size_t)(2+d)*128*512;
    for (int k=0;k<128;k++) acc += h[d][k]*T[(size_t)k*512+gate];
    gbuf[d][gate] = acc;
    __syncthreads();
    if (tid < 256){
      int d2 = tid>>7, i = tid&127;
      int t2 = (d2==0)? s : 1-s;
      float ii = sigmf(gbuf[d2][i]);
      float ff = sigmf(gbuf[d2][128+i]);
      float gg = tanhf(gbuf[d2][256+i]);
      float oo = sigmf(gbuf[d2][384+i]);
      float cn = ff*c[d2][i] + ii*gg;
      c[d2][i] = cn;
      float hn = oo*tanhf(cn);
      h[d2][i] = hn;
      if (t2==1) y1last[d2*128+i] = hn;
    }
    __syncthreads();
  }
  // final FC + softmax
  if (tid < 256){
    sb[tid]  = y1last[tid]*P.fc_w[tid*2+0];
    sb2[tid] = y1last[tid]*P.fc_w[tid*2+1];
  }
  __syncthreads();
  for (int s=128;s>0;s>>=1){
    if (tid<s){ sb[tid]+=sb[tid+s]; sb2[tid]+=sb2[tid+s]; }
    __syncthreads();
  }
  if (tid==0){
    float l0 = sb[0] + P.fc_b[0];
    float l1 = sb2[0] + P.fc_b[1];
    float m = fmaxf(l0,l1);
    float e0 = expf(l0-m), e1 = expf(l1-m), inv = 1.f/(e0+e1);
    P.out[0] = e0*inv;
    P.out[1] = e1*inv;
  }
}

extern "C" void kernel_launch(void* const* d_in, const int* in_sizes, int n_in,
                              void* d_out, int out_size, void* d_ws, size_t ws_size,
                              hipStream_t stream){
  Params P;
  for (int g=0; g<2; ++g){
    int b = g*5;
    P.g[g].feat  = (const float*)d_in[b+0];
    P.g[g].eidx  = (const int*)d_in[b+1];
    P.g[g].eattr = (const float*)d_in[b+2];
    P.g[g].adj   = (const float*)d_in[b+3];
    P.g[g].n2n   = (const float*)d_in[b+4];
  }
  P.W_h   = (const float*)d_in[10];
  P.W_gat = (const float*)d_in[11];
  P.a_src = (const float*)d_in[12];
  P.a_dst = (const float*)d_in[13];
  P.a_e   = (const float*)d_in[14];
  P.We_gat= (const float*)d_in[15];
  P.W_out = (const float*)d_in[16];
  P.ao_src= (const float*)d_in[17];
  P.ao_dst= (const float*)d_in[18];
  P.ao_e  = (const float*)d_in[19];
  P.We_out= (const float*)d_in[20];
  P.ep1_w = (const float*)d_in[21];
  P.ep1_b = (const float*)d_in[22];
  P.ep2_w = (const float*)d_in[23];
  P.ep2_b = (const float*)d_in[24];
  P.g1_w  = (const float*)d_in[25];
  P.g1_b  = (const float*)d_in[26];
  P.g2_w  = (const float*)d_in[27];
  P.g2_b  = (const float*)d_in[28];
  P.g3_w  = (const float*)d_in[29];
  P.g3_b  = (const float*)d_in[30];
  P.Wih0  = (const float*)d_in[31];
  P.Whh0  = (const float*)d_in[32];
  P.b0    = (const float*)d_in[33];
  P.Wih1  = (const float*)d_in[34];
  P.Whh1  = (const float*)d_in[35];
  P.b1    = (const float*)d_in[36];
  P.fc_w  = (const float*)d_in[37];
  P.fc_b  = (const float*)d_in[38];
  P.out   = (float*)d_out;

  // ---- graph stages (14 dispatches) ----
  k_init <<<dim3(IB_Z+IB_C+IB_D+IB_E+IB_H), 256, 0, stream>>>(P);
  k_pairs<<<dim3((E+255)/256,2), 256, 0, stream>>>(P);
  k_e2p  <<<dim3(E/TE2,NH,2),128, 0, stream>>>(P);
  k_Wh   <<<dim3(N,NH+1,2), 128, 0, stream>>>(P);   // +gpool1 slice
  k_att1 <<<dim3(N/4,NH,2),128, 0, stream>>>(P);
  k_xw1  <<<dim3(N,2),    256, 0, stream>>>(P);
  k_s1   <<<dim3((E+255)/256,2), 256, 0, stream>>>(P);
  k_gpool_out<<<dim3(8,2), 256, 0, stream>>>(P, OH1, CAT, ODEG1, ORAW2, P.g2_b, HID);
  k_Wh2  <<<dim3(N,2),    512, 0, stream>>>(P);
  k_att2 <<<dim3(N,2),    128, 0, stream>>>(P);
  k_ew2fin<<<dim3(E/TE2,2),128, 0, stream>>>(P);    // +s2
  k_gpool_out<<<dim3(1,2), 256, 0, stream>>>(P, OH2B, OUTD, ODEG2, ORAW3, P.g3_b, HID+CAT);
  k_lstm_xg <<<dim3(512), 256, 0, stream>>>(P);
  k_mega <<<dim3(1), 1024, 0, stream>>>(P);         // rec0+xg1+rec1+final
}

// Round 17
// 428.438 us; speedup vs baseline: 1.4624x; 1.4624x over previous
//
#include <hip/hip_runtime.h>
#include <math.h>

#define DI static __device__ __forceinline__

DI float eluf(float x){ return x > 0.f ? x : expm1f(x); }
DI float lreluf(float x){ return x > 0.f ? x : 0.2f*x; }
DI float sigmf(float x){ return 1.f/(1.f+expf(-x)); }

constexpr int N=200, E=3200, HID=64, NH=16, OUTD=128, CAT=2048, SEQD=2240;

// ---- per-graph f32 scratch offsets (in floats) ----
constexpr int OH0   = 0;
constexpr int OWH   = OH0 + N*HID;
constexpr int OASN  = OWH + NH*N*OUTD;
constexpr int OADN  = OASN + NH*N;
constexpr int OH1   = OADN + NH*N;
constexpr int OXW1  = OH1 + N*CAT;
constexpr int OXW2  = OXW1 + 256;
constexpr int OEW1  = OXW2 + 256;
constexpr int OS1   = OEW1 + E;
constexpr int ODEG1 = OS1 + E;
constexpr int OSS1  = ODEG1 + 256;   // = ODEG1+256 (inline ns relies on this)
constexpr int ORAW1 = OSS1 + 256;
constexpr int OWH2  = ORAW1 + 256;
constexpr int OAS2  = OWH2 + N*OUTD;
constexpr int OAD2  = OAS2 + 256;
constexpr int OEWV  = OAD2 + 256;
constexpr int OH2B  = OEWV + E;
constexpr int OXS2  = OH2B + N*OUTD;
constexpr int OXD2  = OXS2 + 256;
constexpr int ODEG2 = OXD2 + 256;
constexpr int OSS2  = ODEG2 + 256;   // = ODEG2+256
constexpr int ORAW2 = OSS2 + 256;
constexpr int ORAW3 = ORAW2 + 256;
constexpr int PGF   = ORAW3 + 256;
constexpr int GLOBF = 10624;
constexpr int TOTF  = GLOBF + 2*PGF;

// ---- static device scratch ----
__device__ float G_F[TOTF];
__device__ float G_E2PART[(size_t)NH*2*E*OUTD];
__device__ float G_EDOTH[2*NH*E];
__device__ float G_WHHT[2*2*128*512];
__device__ int   G_PIDX[2*N*N];

DI float* gf(int g){ return G_F + GLOBF + (size_t)g*PGF; }
DI float* gwe_ae(){ return G_F; }
DI float* gv_e(){ return G_F + 1024; }
DI float* gy0(){ return G_F + 3072; }
DI float* gy1(){ return G_F + 3584; }
DI float* gxseq(){ return G_F + 4096; }
DI float* gxg(){ return G_F + 8576; }
DI int*   gpidx(int g){ return G_PIDX + g*N*N; }

struct GraphIn {
  const float *feat, *eattr, *adj, *n2n;
  const int   *eidx;
};

struct Params {
  GraphIn g[2];
  const float *W_h, *W_gat, *a_src, *a_dst, *a_e, *We_gat;
  const float *W_out, *ao_src, *ao_dst, *ao_e, *We_out;
  const float *ep1_w, *ep1_b, *ep2_w, *ep2_b;
  const float *g1_w, *g1_b, *g2_w, *g2_b, *g3_w, *g3_b;
  const float *Wih0, *Whh0, *b0, *Wih1, *Whh1, *b1, *fc_w, *fc_b;
  float *out;
};

// ---- fused init: zero atomic targets, pidx=-1, Whh transpose, precontract, h0+g1dot ----
constexpr int ZPG  = 2*E + 1024;              // per-graph floats to zero
constexpr int IB_Z = (2*ZPG+255)/256;
constexpr int IB_C = (2*N*N+255)/256;
constexpr int IB_D = (2*2*512*128)/256;
constexpr int IB_E = (NH*HID+CAT+3)/4;
constexpr int IB_H = (2*N+3)/4;
__global__ void k_init(Params P){
  int b = blockIdx.x, tid = threadIdx.x;
  if (b < IB_Z){
    int i = b*256 + tid;
    if (i < 2*ZPG){
      int g = i/ZPG, r = i%ZPG;
      int addr = r<E ? OEW1+r : (r<2*E ? OEWV+(r-E) :
                 (r<2*E+512 ? ODEG1+(r-2*E) : ODEG2+(r-2*E-512)));
      gf(g)[addr] = 0.f;
    }
  } else if (b < IB_Z+IB_C){
    int i = (b-IB_Z)*256 + tid; if (i < 2*N*N) G_PIDX[i] = -1;
  } else if (b < IB_Z+IB_C+IB_D){
    int idx = (b-IB_Z-IB_C)*256 + tid;
    int l = idx >> 17;
    int r = idx & 131071;
    int d = r >> 16;
    int r2 = r & 65535;
    int gate = r2 & 511;
    int k = r2 >> 9;
    const float* Whh = l ? P.Whh1 : P.Whh0;
    G_WHHT[idx] = Whh[((size_t)d*512+gate)*128 + k];
  } else if (b < IB_Z+IB_C+IB_D+IB_E){
    int gid = (b-IB_Z-IB_C-IB_D)*4 + (tid>>6);
    int lane = tid & 63;
    if (gid < NH*HID){
      int h = gid/HID, c = gid%HID;
      const float* W = P.We_gat + (size_t)(h*HID+c)*OUTD;
      const float* a = P.a_e + h*OUTD;
      float acc = 0.f;
      for (int o=lane;o<OUTD;o+=64) acc += W[o]*a[o];
      for (int off=32;off>0;off>>=1) acc += __shfl_down(acc,off);
      if (lane==0) gwe_ae()[gid] = acc;
    } else if (gid < NH*HID+CAT){
      int c = gid - NH*HID;
      const float* W = P.We_out + (size_t)c*OUTD;
      float acc = 0.f;
      for (int o=lane;o<OUTD;o+=64) acc += W[o]*P.ao_e[o];
      for (int off=32;off>0;off>>=1) acc += __shfl_down(acc,off);
      if (lane==0) gv_e()[c] = acc;
    }
  } else {
    int unit = (b-IB_Z-IB_C-IB_D-IB_E)*4 + (tid>>6);
    if (unit >= 2*N) return;
    int g = unit / N, n = unit % N, c = tid & 63;
    const float* feat = P.g[g].feat;
    float acc = 0.f;
    for (int k=0;k<HID;k++) acc += feat[n*HID+k]*P.W_h[k*HID+c];
    float v = eluf(acc);
    float* f = gf(g);
    f[OH0 + n*HID + c] = v;
    float r = v*P.g1_w[c];
    for (int off=32;off>0;off>>=1) r += __shfl_down(r,off);
    if (c==0) f[ORAW1+n] = r;
  }
}

// ---- Wh[h] = h0 @ W_gat[h] + fused asn/adn; y==NH slice does gpool1 output ----
__global__ void k_Wh(Params P){
  int n = blockIdx.x, h = blockIdx.y, g = blockIdx.z, o = threadIdx.x;
  float* f = gf(g);
  if (h == NH){
    if (n != 0) return;
    __shared__ float att[N];
    __shared__ float sb[128];
    for (int j = o; j < N; j += 128) att[j] = sigmf(f[ORAW1+j] + P.g1_b[0]);
    __syncthreads();
    float m = -3e38f;
    for (int j = o; j < N; j += 128) m = fmaxf(m, att[j]);
    sb[o] = m; __syncthreads();
    for (int s=64;s>0;s>>=1){ if (o<s) sb[o]=fmaxf(sb[o],sb[o+s]); __syncthreads(); }
    m = sb[0]; __syncthreads();
    float ss = 0.f;
    for (int j = o; j < N; j += 128){ float e = expf(att[j]-m); ss += e; }
    sb[o] = ss; __syncthreads();
    for (int s=64;s>0;s>>=1){ if (o<s) sb[o]+=sb[o+s]; __syncthreads(); }
    float inv = 1.f/sb[0]; __syncthreads();
    for (int j = o; j < N; j += 128) att[j] = expf(att[j]-m)*inv;
    __syncthreads();
    if (o < HID){
      float acc = 0.f;
      for (int j=0;j<N;j++) acc += att[j]*f[OH0 + j*HID + o];
      gxseq()[g*SEQD + o] = acc;
    }
    return;
  }
  __shared__ float hs[HID];
  __shared__ float sred[128], dred[128];
  if (o < HID) hs[o] = f[OH0 + n*HID + o];
  __syncthreads();
  const float* W = P.W_gat + (size_t)h*HID*OUTD + o;
  float acc = 0.f;
  for (int c=0;c<HID;c++) acc += hs[c]*W[(size_t)c*OUTD];
  f[OWH + ((size_t)h*N + n)*OUTD + o] = acc;
  sred[o] = acc*P.a_src[h*OUTD+o];
  dred[o] = acc*P.a_dst[h*OUTD+o];
  __syncthreads();
  for (int s=64;s>0;s>>=1){ if (o<s){ sred[o]+=sred[o+s]; dred[o]+=dred[o+s]; } __syncthreads(); }
  if (o==0){ f[OASN+h*N+n]=sred[0]; f[OADN+h*N+n]=dred[0]; }
}

// ---- GAT layer 1: 4 nodes/block ----
__global__ void k_att1(Params P){
  int nb = blockIdx.x, h = blockIdx.y, g = blockIdx.z, tid = threadIdx.x;
  int n0 = nb*4;
  __shared__ float z[4][N];
  __shared__ float red[128];
  __shared__ float sinv[4];
  float* f = gf(g);
  const float* adj = P.g[g].adj;
  const int* pidx = gpidx(g);
  const float* edoth = G_EDOTH + ((size_t)g*NH + h)*E;
  const float* adn = f + OADN + h*N;
  for (int i=0;i<4;i++){
    float asn = f[OASN + h*N + n0+i];
    for (int j = tid; j < N; j += 128){
      float a = adj[(n0+i)*N + j];
      float zz;
      if (a > 0.f){
        int p = pidx[(n0+i)*N + j];
        float ee = (p >= 0) ? edoth[p] : 0.f;
        zz = lreluf(asn + adn[j] + ee);
      } else zz = -1e9f;
      z[i][j] = zz;
    }
  }
  __syncthreads();
  for (int i=0;i<4;i++){
    float m = -3e38f;
    for (int j = tid; j < N; j += 128) m = fmaxf(m, z[i][j]);
    red[tid] = m; __syncthreads();
    for (int s=64;s>0;s>>=1){ if (tid<s) red[tid]=fmaxf(red[tid],red[tid+s]); __syncthreads(); }
    m = red[0]; __syncthreads();
    float ssum = 0.f;
    for (int j = tid; j < N; j += 128){ float e = expf(z[i][j]-m); z[i][j]=e; ssum += e; }
    red[tid] = ssum; __syncthreads();
    for (int s=64;s>0;s>>=1){ if (tid<s) red[tid]+=red[tid+s]; __syncthreads(); }
    if (tid==0) sinv[i] = 1.f/red[0];
    __syncthreads();
  }
  const float* wh = f + OWH + (size_t)h*N*OUTD;
  float a0=0.f,a1=0.f,a2=0.f,a3=0.f;
  for (int j=0;j<N;j++){
    float w = wh[(size_t)j*OUTD + tid];
    a0 += z[0][j]*w; a1 += z[1][j]*w; a2 += z[2][j]*w; a3 += z[3][j]*w;
  }
  f[OH1 + (size_t)(n0+0)*CAT + h*OUTD + tid] = eluf(a0*sinv[0]);
  f[OH1 + (size_t)(n0+1)*CAT + h*OUTD + tid] = eluf(a1*sinv[1]);
  f[OH1 + (size_t)(n0+2)*CAT + h*OUTD + tid] = eluf(a2*sinv[2]);
  f[OH1 + (size_t)(n0+3)*CAT + h*OUTD + tid] = eluf(a3*sinv[3]);
}

// ---- pool1 node dots + fused g2 raw gate dot ----
__global__ void k_xw1(Params P){
  int n = blockIdx.x, g = blockIdx.y, tid = threadIdx.x;
  __shared__ float s1b[256], s2b[256], s3b[256];
  float* f = gf(g);
  const float* x = f + OH1 + (size_t)n*CAT;
  float a1 = 0.f, a2 = 0.f, a3 = 0.f;
  for (int c = tid; c < CAT; c += 256){
    float xv = x[c];
    a1 += xv*P.ep1_w[c];
    a2 += xv*P.ep1_w[CAT+c];
    a3 += xv*P.g2_w[c];
  }
  s1b[tid]=a1; s2b[tid]=a2; s3b[tid]=a3; __syncthreads();
  for (int s=128;s>0;s>>=1){
    if (tid<s){ s1b[tid]+=s1b[tid+s]; s2b[tid]+=s2b[tid+s]; s3b[tid]+=s3b[tid+s]; }
    __syncthreads();
  }
  if (tid==0){ f[OXW1+n]=s1b[0]; f[OXW2+n]=s2b[0]; f[ORAW2+n]=s3b[0]; }
}

// ---------------- pool1 edge scores + segment sums ----------------
__global__ void k_s1(Params P){
  int e = blockIdx.x*256 + threadIdx.x, g = blockIdx.y;
  if (e >= E) return;
  float* f = gf(g);
  const int* ei = P.g[g].eidx;
  int s = ei[e], d = ei[E+e];
  float v = sigmf(f[OXW1+s] + f[OXW2+d] + f[OEW1+e] + P.ep1_b[0]);
  f[OS1+e] = v;
  atomicAdd(&f[OSS1+s], v);
  atomicAdd(&f[ODEG1+s], 1.f);
}

// ---------------- pairIdx: last edge wins ----------------
__global__ void k_pairs(Params P){
  int e = blockIdx.x*256 + threadIdx.x, g = blockIdx.y;
  if (e >= E) return;
  const int* ei = P.g[g].eidx;
  atomicMax(&gpidx(g)[ei[e]*N + ei[E+e]], e);
}

// ---- gpool output (pools 2/3): inline gate; column-tiled ----
__global__ void k_gpool_out(Params P, int xoff, int D, int odeg, int rawoff,
                            const float* b, int outoff){
  int cb = blockIdx.x, g = blockIdx.y, tid = threadIdx.x;
  __shared__ float att[N];
  __shared__ float sb[256];
  float* f = gf(g);
  for (int n = tid; n < N; n += 256){
    float sc = f[odeg+256+n]/(f[odeg+n]+1e-6f);
    att[n] = sigmf(f[rawoff+n]*sc + b[0]);
  }
  __syncthreads();
  float m = -3e38f;
  for (int n = tid; n < N; n += 256) m = fmaxf(m, att[n]);
  sb[tid] = m; __syncthreads();
  for (int s=128;s>0;s>>=1){ if (tid<s) sb[tid]=fmaxf(sb[tid],sb[tid+s]); __syncthreads(); }
  m = sb[0]; __syncthreads();
  float ss = 0.f;
  for (int n = tid; n < N; n += 256){ float e = expf(att[n]-m); ss += e; }
  sb[tid] = ss; __syncthreads();
  for (int s=128;s>0;s>>=1){ if (tid<s) sb[tid]+=sb[tid+s]; __syncthreads(); }
  float inv = 1.f/sb[0]; __syncthreads();
  for (int n = tid; n < N; n += 256){
    float sc = f[odeg+256+n]/(f[odeg+n]+1e-6f);
    att[n] = expf(att[n]-m)*inv*sc;
  }
  __syncthreads();
  int c = cb*256 + tid;
  if (c < D){
    const float* x = f + xoff;
    float acc = 0.f;
    for (int n=0;n<N;n++) acc += att[n]*x[(size_t)n*D + c];
    gxseq()[g*SEQD + outoff + c] = acc;
  }
}

// ---- Wh2 (N,2; 512 thr) + fused asad2 tail ----
__global__ void k_Wh2(Params P){
  int n = blockIdx.x, g = blockIdx.y, tid = threadIdx.x;
  int kq = tid >> 7, o = tid & 127;
  __shared__ float hrow[4][128];
  __shared__ float part[4][128];
  __shared__ float sr[128], dr[128];
  float* f = gf(g);
  const float* x = f + OH1 + (size_t)n*CAT;
  float acc = 0.f;
  for (int cc=0; cc<4; cc++){
    int c0 = kq*512 + cc*128;
    __syncthreads();
    hrow[kq][o] = x[c0 + o];
    __syncthreads();
    const float* W = P.W_out + (size_t)c0*OUTD + o;
    for (int j=0;j<128;j++) acc += hrow[kq][j]*W[(size_t)j*OUTD];
  }
  part[kq][o] = acc;
  __syncthreads();
  if (kq==0){
    float ns = f[OSS1+n]/(f[ODEG1+n]+1e-6f);
    float a = part[0][o]+part[1][o]+part[2][o]+part[3][o];
    float v = a*ns;
    f[OWH2 + (size_t)n*OUTD + o] = v;
    sr[o] = v*P.ao_src[o];
    dr[o] = v*P.ao_dst[o];
  }
  __syncthreads();
  for (int s=64;s>0;s>>=1){
    if (tid<s){ sr[tid]+=sr[tid+s]; dr[tid]+=dr[tid+s]; }
    __syncthreads();
  }
  if (tid==0){ f[OAS2+n]=sr[0]; f[OAD2+n]=dr[0]; }
}

// ---- GAT layer 2; fused xs2/xd2 + g3 raw gate dot ----
__global__ void k_att2(Params P){
  int n = blockIdx.x, g = blockIdx.y, tid = threadIdx.x;
  __shared__ float z[N];
  __shared__ float red[128];
  __shared__ float dred[128];
  __shared__ float gred[128];
  float* f = gf(g);
  const float* adj = P.g[g].adj;
  const int* pidx = gpidx(g);
  float asn = f[OAS2+n];
  const float* adn = f + OAD2;
  for (int j = tid; j < N; j += 128){
    float a = adj[n*N + j];
    float zz;
    if (a > 0.f){
      int p = pidx[n*N + j];
      float ee = (p >= 0) ? f[OEWV+p]*f[OS1+p] : 0.f;
      zz = lreluf(asn + adn[j] + ee);
    } else zz = -1e9f;
    z[j] = zz;
  }
  __syncthreads();
  float m = -3e38f;
  for (int j = tid; j < N; j += 128) m = fmaxf(m, z[j]);
  red[tid] = m; __syncthreads();
  for (int s=64;s>0;s>>=1){ if (tid<s) red[tid]=fmaxf(red[tid],red[tid+s]); __syncthreads(); }
  m = red[0]; __syncthreads();
  float ssum = 0.f;
  for (int j = tid; j < N; j += 128){ float e = expf(z[j]-m); z[j]=e; ssum += e; }
  red[tid] = ssum; __syncthreads();
  for (int s=64;s>0;s>>=1){ if (tid<s) red[tid]+=red[tid+s]; __syncthreads(); }
  float inv = 1.f/red[0]; __syncthreads();
  const float* wh = f + OWH2;
  float acc = 0.f;
  for (int j=0;j<N;j++){
    float w = z[j];
    if (w != 0.f) acc += w * wh[(size_t)j*OUTD + tid];
  }
  float v = acc*inv;
  f[OH2B + (size_t)n*OUTD + tid] = v;
  red[tid]  = v*P.ep2_w[tid];
  dred[tid] = v*P.ep2_w[OUTD+tid];
  gred[tid] = v*P.g3_w[tid];
  __syncthreads();
  for (int s=64;s>0;s>>=1){
    if (tid<s){ red[tid]+=red[tid+s]; dred[tid]+=dred[tid+s]; gred[tid]+=gred[tid+s]; }
    __syncthreads();
  }
  if (tid==0){ f[OXS2+n]=red[0]; f[OXD2+n]=dred[0]; f[ORAW3+n]=gred[0]; }
}

// ---- e2 partial: register-tiled 4x4, fused ew1/ewv + EDOTH ----
constexpr int TE2 = 16;
__global__ __launch_bounds__(128, 2) void k_e2p(Params P){
  int e0 = blockIdx.x*TE2, h = blockIdx.y, g = blockIdx.z, tid = threadIdx.x;
  int cg = tid & 31, eg = tid >> 5;
  int c4 = cg*4, e4 = eg*4;
  __shared__ float es_t[HID][TE2+1];
  __shared__ float tcol_t[OUTD][TE2];
  const float* __restrict__ ea = P.g[g].eattr + (size_t)e0*HID;
  for (int i = tid; i < TE2*HID; i += 128) es_t[i & 63][i >> 6] = ea[i];
  __syncthreads();
  const float* __restrict__ W1 = P.We_gat + (size_t)h*HID*OUTD;
  const float* __restrict__ weae = gwe_ae() + h*HID;
  float t[4][4];
  float ed[4] = {0.f,0.f,0.f,0.f};
  #pragma unroll
  for (int i=0;i<4;i++){ t[i][0]=0.f; t[i][1]=0.f; t[i][2]=0.f; t[i][3]=0.f; }
  for (int c=0;c<HID;c++){
    float ev0 = es_t[c][e4+0], ev1 = es_t[c][e4+1], ev2 = es_t[c][e4+2], ev3 = es_t[c][e4+3];
    float4 w  = *(const float4*)&W1[(size_t)c*OUTD + c4];
    t[0][0]+=ev0*w.x; t[0][1]+=ev0*w.y; t[0][2]+=ev0*w.z; t[0][3]+=ev0*w.w;
    t[1][0]+=ev1*w.x; t[1][1]+=ev1*w.y; t[1][2]+=ev1*w.z; t[1][3]+=ev1*w.w;
    t[2][0]+=ev2*w.x; t[2][1]+=ev2*w.y; t[2][2]+=ev2*w.z; t[2][3]+=ev2*w.w;
    t[3][0]+=ev3*w.x; t[3][1]+=ev3*w.y; t[3][2]+=ev3*w.z; t[3][3]+=ev3*w.w;
    float wc = weae[c];
    ed[0]+=ev0*wc; ed[1]+=ev1*wc; ed[2]+=ev2*wc; ed[3]+=ev3*wc;
  }
  if (cg==0){
    float* eo = G_EDOTH + ((size_t)g*NH+h)*E + e0 + e4;
    eo[0]=ed[0]; eo[1]=ed[1]; eo[2]=ed[2]; eo[3]=ed[3];
  }
  #pragma unroll
  for (int i=0;i<4;i++){
    t[i][0]=eluf(t[i][0]); t[i][1]=eluf(t[i][1]); t[i][2]=eluf(t[i][2]); t[i][3]=eluf(t[i][3]);
  }
  {
    float4 w1 = *(const float4*)&P.ep1_w[2*CAT + h*OUTD + c4];
    float4 wv = *(const float4*)&gv_e()[h*OUTD + c4];
    #pragma unroll
    for (int i=0;i<4;i++){
      float a1 = t[i][0]*w1.x + t[i][1]*w1.y + t[i][2]*w1.z + t[i][3]*w1.w;
      float a2 = t[i][0]*wv.x + t[i][1]*wv.y + t[i][2]*wv.z + t[i][3]*wv.w;
      for (int off=16;off>0;off>>=1){
        a1 += __shfl_down(a1,off,32);
        a2 += __shfl_down(a2,off,32);
      }
      if (cg==0){
        atomicAdd(&gf(g)[OEW1 + e0+e4+i], a1);
        atomicAdd(&gf(g)[OEWV + e0+e4+i], a2);
      }
    }
  }
  #pragma unroll
  for (int j=0;j<4;j++){
    int o = c4 + j;
    int slot = (eg + (o>>2)) & 3;
    float4 v; v.x=t[0][j]; v.y=t[1][j]; v.z=t[2][j]; v.w=t[3][j];
    *(float4*)&tcol_t[o][4*slot] = v;
  }
  __syncthreads();
  const float* __restrict__ W2 = P.We_out + (size_t)h*OUTD*OUTD;
  float acc[4][4];
  #pragma unroll
  for (int i=0;i<4;i++){ acc[i][0]=0.f; acc[i][1]=0.f; acc[i][2]=0.f; acc[i][3]=0.f; }
  #pragma unroll 4
  for (int o=0;o<OUTD;o++){
    int slot = (eg + (o>>2)) & 3;
    float4 tv = *(const float4*)&tcol_t[o][4*slot];
    float4 w  = *(const float4*)&W2[(size_t)o*OUTD + c4];
    acc[0][0]+=tv.x*w.x; acc[0][1]+=tv.x*w.y; acc[0][2]+=tv.x*w.z; acc[0][3]+=tv.x*w.w;
    acc[1][0]+=tv.y*w.x; acc[1][1]+=tv.y*w.y; acc[1][2]+=tv.y*w.z; acc[1][3]+=tv.y*w.w;
    acc[2][0]+=tv.z*w.x; acc[2][1]+=tv.z*w.y; acc[2][2]+=tv.z*w.z; acc[2][3]+=tv.z*w.w;
    acc[3][0]+=tv.w*w.x; acc[3][1]+=tv.w*w.y; acc[3][2]+=tv.w*w.z; acc[3][3]+=tv.w*w.w;
  }
  float* dst = G_E2PART + (((size_t)h*2 + g)*E + e0)*OUTD;
  #pragma unroll
  for (int i=0;i<4;i++){
    float4 v; v.x=acc[i][0]; v.y=acc[i][1]; v.z=acc[i][2]; v.w=acc[i][3];
    *(float4*)&dst[(size_t)(e4+i)*OUTD + c4] = v;
  }
}

// ---- finish: sum head-partials, elu, dot ep2_w; fused s2 scoring + segment sums ----
__global__ void k_ew2fin(Params P){
  int e0 = blockIdx.x*TE2, g = blockIdx.y, tid = threadIdx.x;
  __shared__ float lred[2][TE2];
  float* f = gf(g);
  float w2 = P.ep2_w[2*OUTD + tid];
  int lane = tid & 63, wvi = tid >> 6;
  for (int e=0;e<TE2;e++){
    const float* src = G_E2PART + ((size_t)g*E + e0 + e)*OUTD + tid;
    float a = 0.f;
    for (int h=0;h<NH;h++) a += src[(size_t)h*2*E*OUTD];
    float v = eluf(f[OS1+e0+e]*a) * w2;
    for (int off=32;off>0;off>>=1) v += __shfl_down(v,off);
    if (lane==0) lred[wvi][e]=v;
  }
  __syncthreads();
  if (tid < TE2){
    int e = e0 + tid;
    float ew2 = lred[0][tid]+lred[1][tid];
    const int* ei = P.g[g].eidx;
    int s = ei[e], d = ei[E+e];
    float v = sigmf(f[OXS2+s] + f[OXD2+d] + ew2 + P.ep2_b[0]);
    atomicAdd(&f[OSS2+s], v);
    atomicAdd(&f[ODEG2+s], 1.f);
  }
}

// ---- LSTM input projection ----
__global__ void k_lstm_xg(Params P, int layer){
  int gid = blockIdx.x*4 + (threadIdx.x>>6);
  int lane = threadIdx.x & 63;
  int t = gid >> 10;
  int rem = gid & 1023;
  int d = rem >> 9;
  int gate = rem & 511;
  const float* Wih = layer ? P.Wih1 : P.Wih0;
  const float* bb  = layer ? P.b1   : P.b0;
  const float* xin = layer ? gy0()  : gxseq();
  int Din = layer ? 256 : SEQD;
  const float* x = xin + t*Din;
  const float* Wr = Wih + ((size_t)d*512 + gate)*Din;
  float acc = 0.f;
  for (int k=lane; k<Din; k+=64) acc += x[k]*Wr[k];
  for (int off=32; off>0; off>>=1) acc += __shfl_down(acc, off);
  if (lane==0) gxg()[(t*2 + d)*512 + gate] = acc + bb[d*512 + gate];
}

// ---- LSTM recurrence: coalesced via transposed Whh ----
__global__ void k_lstm_rec(Params P, int layer){
  int d = blockIdx.x, tid = threadIdx.x;
  float* yout = layer ? gy1() : gy0();
  const float* T = G_WHHT + (size_t)(layer*2 + d)*128*512;
  __shared__ float h[128], c[128], gbuf[512];
  if (tid < 128){ h[tid]=0.f; c[tid]=0.f; }
  __syncthreads();
  for (int s=0;s<2;s++){
    int t = (d==0) ? s : 1-s;
    float acc = gxg()[(t*2 + d)*512 + tid];
    for (int k=0;k<128;k++) acc += h[k]*T[(size_t)k*512 + tid];
    gbuf[tid] = acc;
    __syncthreads();
    if (tid < 128){
      float ii = sigmf(gbuf[tid]);
      float ff = sigmf(gbuf[128+tid]);
      float gg = tanhf(gbuf[256+tid]);
      float oo = sigmf(gbuf[384+tid]);
      float cn = ff*c[tid] + ii*gg;
      c[tid] = cn;
      float hn = oo*tanhf(cn);
      h[tid] = hn;
      yout[t*256 + d*128 + tid] = hn;
    }
    __syncthreads();
  }
}

// ---------------- final FC + softmax ----------------
__global__ void k_final(Params P){
  int tid = threadIdx.x;
  __shared__ float sb[256], sb2[256];
  const float* x = gy1() + 256;
  sb[tid]  = x[tid]*P.fc_w[tid*2+0];
  sb2[tid] = x[tid]*P.fc_w[tid*2+1];
  __syncthreads();
  for (int s=128;s>0;s>>=1){ if (tid<s){ sb[tid]+=sb[tid+s]; sb2[tid]+=sb2[tid+s]; } __syncthreads(); }
  if (tid==0){
    float l0 = sb[0] + P.fc_b[0];
    float l1 = sb2[0] + P.fc_b[1];
    float m = fmaxf(l0,l1);
    float e0 = expf(l0-m), e1 = expf(l1-m), inv = 1.f/(e0+e1);
    P.out[0] = e0*inv;
    P.out[1] = e1*inv;
  }
}

extern "C" void kernel_launch(void* const* d_in, const int* in_sizes, int n_in,
                              void* d_out, int out_size, void* d_ws, size_t ws_size,
                              hipStream_t stream){
  Params P;
  for (int g=0; g<2; ++g){
    int b = g*5;
    P.g[g].feat  = (const float*)d_in[b+0];
    P.g[g].eidx  = (const int*)d_in[b+1];
    P.g[g].eattr = (const float*)d_in[b+2];
    P.g[g].adj   = (const float*)d_in[b+3];
    P.g[g].n2n   = (const float*)d_in[b+4];
  }
  P.W_h   = (const float*)d_in[10];
  P.W_gat = (const float*)d_in[11];
  P.a_src = (const float*)d_in[12];
  P.a_dst = (const float*)d_in[13];
  P.a_e   = (const float*)d_in[14];
  P.We_gat= (const float*)d_in[15];
  P.W_out = (const float*)d_in[16];
  P.ao_src= (const float*)d_in[17];
  P.ao_dst= (const float*)d_in[18];
  P.ao_e  = (const float*)d_in[19];
  P.We_out= (const float*)d_in[20];
  P.ep1_w = (const float*)d_in[21];
  P.ep1_b = (const float*)d_in[22];
  P.ep2_w = (const float*)d_in[23];
  P.ep2_b = (const float*)d_in[24];
  P.g1_w  = (const float*)d_in[25];
  P.g1_b  = (const float*)d_in[26];
  P.g2_w  = (const float*)d_in[27];
  P.g2_b  = (const float*)d_in[28];
  P.g3_w  = (const float*)d_in[29];
  P.g3_b  = (const float*)d_in[30];
  P.Wih0  = (const float*)d_in[31];
  P.Whh0  = (const float*)d_in[32];
  P.b0    = (const float*)d_in[33];
  P.Wih1  = (const float*)d_in[34];
  P.Whh1  = (const float*)d_in[35];
  P.b1    = (const float*)d_in[36];
  P.fc_w  = (const float*)d_in[37];
  P.fc_b  = (const float*)d_in[38];
  P.out   = (float*)d_out;

  // ---- graph stages (17 dispatches) ----
  k_init <<<dim3(IB_Z+IB_C+IB_D+IB_E+IB_H), 256, 0, stream>>>(P);
  k_pairs<<<dim3((E+255)/256,2), 256, 0, stream>>>(P);
  k_e2p  <<<dim3(E/TE2,NH,2),128, 0, stream>>>(P);
  k_Wh   <<<dim3(N,NH+1,2), 128, 0, stream>>>(P);   // +gpool1 slice
  k_att1 <<<dim3(N/4,NH,2),128, 0, stream>>>(P);
  k_xw1  <<<dim3(N,2),    256, 0, stream>>>(P);
  k_s1   <<<dim3((E+255)/256,2), 256, 0, stream>>>(P);
  k_gpool_out<<<dim3(8,2), 256, 0, stream>>>(P, OH1, CAT, ODEG1, ORAW2, P.g2_b, HID);
  k_Wh2  <<<dim3(N,2),    512, 0, stream>>>(P);
  k_att2 <<<dim3(N,2),    128, 0, stream>>>(P);
  k_ew2fin<<<dim3(E/TE2,2),128, 0, stream>>>(P);    // +s2
  k_gpool_out<<<dim3(1,2), 256, 0, stream>>>(P, OH2B, OUTD, ODEG2, ORAW3, P.g3_b, HID+CAT);

  // ---- LSTM stack + classifier (R15 proven form) ----
  k_lstm_xg <<<dim3(512), 256, 0, stream>>>(P, 0);
  k_lstm_rec<<<dim3(2),   512, 0, stream>>>(P, 0);
  k_lstm_xg <<<dim3(2),   256, 0, stream>>>(P, 1);
  k_lstm_rec<<<dim3(2),   512, 0, stream>>>(P, 1);
  k_final<<<dim3(1), 256, 0, stream>>>(P);
}

// Round 18
// 424.659 us; speedup vs baseline: 1.4754x; 1.0089x over previous
//
#include <hip/hip_runtime.h>
#include <math.h>

#define DI static __device__ __forceinline__

DI float eluf(float x){ return x > 0.f ? x : expm1f(x); }
DI float lreluf(float x){ return x > 0.f ? x : 0.2f*x; }
DI float sigmf(float x){ return 1.f/(1.f+expf(-x)); }

constexpr int N=200, E=3200, HID=64, NH=16, OUTD=128, CAT=2048, SEQD=2240;

// ---- per-graph f32 scratch offsets (in floats) ----
constexpr int OH0   = 0;
constexpr int OWH   = OH0 + N*HID;
constexpr int OASN  = OWH + NH*N*OUTD;
constexpr int OADN  = OASN + NH*N;
constexpr int OH1   = OADN + NH*N;
constexpr int OXW1  = OH1 + N*CAT;
constexpr int OXW2  = OXW1 + 256;
constexpr int OEW1  = OXW2 + 256;
constexpr int OS1   = OEW1 + E;
constexpr int ODEG1 = OS1 + E;
constexpr int OSS1  = ODEG1 + 256;   // = ODEG1+256 (inline ns relies on this)
constexpr int ORAW1 = OSS1 + 256;
constexpr int OWH2  = ORAW1 + 256;
constexpr int OAS2  = OWH2 + N*OUTD;
constexpr int OAD2  = OAS2 + 256;
constexpr int OEWV  = OAD2 + 256;
constexpr int OH2B  = OEWV + E;
constexpr int OXS2  = OH2B + N*OUTD;
constexpr int OXD2  = OXS2 + 256;
constexpr int ODEG2 = OXD2 + 256;
constexpr int OSS2  = ODEG2 + 256;   // = ODEG2+256
constexpr int ORAW2 = OSS2 + 256;
constexpr int ORAW3 = ORAW2 + 256;
constexpr int PGF   = ORAW3 + 256;
constexpr int GLOBF = 10624;
constexpr int TOTF  = GLOBF + 2*PGF;

// ---- static device scratch ----
__device__ float G_F[TOTF];
__device__ float G_E2PART[(size_t)NH*2*E*OUTD];
__device__ float G_EDOTH[2*NH*E];
__device__ float G_WHHT[2*2*128*512];
__device__ int   G_PIDX[2*N*N];

DI float* gf(int g){ return G_F + GLOBF + (size_t)g*PGF; }
DI float* gwe_ae(){ return G_F; }
DI float* gv_e(){ return G_F + 1024; }
DI float* gy0(){ return G_F + 3072; }
DI float* gy1(){ return G_F + 3584; }
DI float* gxseq(){ return G_F + 4096; }
DI float* gxg(){ return G_F + 8576; }
DI int*   gpidx(int g){ return G_PIDX + g*N*N; }

struct GraphIn {
  const float *feat, *eattr, *adj, *n2n;
  const int   *eidx;
};

struct Params {
  GraphIn g[2];
  const float *W_h, *W_gat, *a_src, *a_dst, *a_e, *We_gat;
  const float *W_out, *ao_src, *ao_dst, *ao_e, *We_out;
  const float *ep1_w, *ep1_b, *ep2_w, *ep2_b;
  const float *g1_w, *g1_b, *g2_w, *g2_b, *g3_w, *g3_b;
  const float *Wih0, *Whh0, *b0, *Wih1, *Whh1, *b1, *fc_w, *fc_b;
  float *out;
};

// ---- fused init: zero atomic targets, pidx=-1, Whh transpose, precontract, h0+g1dot ----
constexpr int ZPG  = 2*E + 1024;              // per-graph floats to zero
constexpr int IB_Z = (2*ZPG+255)/256;
constexpr int IB_C = (2*N*N+255)/256;
constexpr int IB_D = (2*2*512*128)/256;
constexpr int IB_E = (NH*HID+CAT+3)/4;
constexpr int IB_H = (2*N+3)/4;
__global__ void k_init(Params P){
  int b = blockIdx.x, tid = threadIdx.x;
  if (b < IB_Z){
    int i = b*256 + tid;
    if (i < 2*ZPG){
      int g = i/ZPG, r = i%ZPG;
      int addr = r<E ? OEW1+r : (r<2*E ? OEWV+(r-E) :
                 (r<2*E+512 ? ODEG1+(r-2*E) : ODEG2+(r-2*E-512)));
      gf(g)[addr] = 0.f;
    }
  } else if (b < IB_Z+IB_C){
    int i = (b-IB_Z)*256 + tid; if (i < 2*N*N) G_PIDX[i] = -1;
  } else if (b < IB_Z+IB_C+IB_D){
    int idx = (b-IB_Z-IB_C)*256 + tid;
    int l = idx >> 17;
    int r = idx & 131071;
    int d = r >> 16;
    int r2 = r & 65535;
    int gate = r2 & 511;
    int k = r2 >> 9;
    const float* Whh = l ? P.Whh1 : P.Whh0;
    G_WHHT[idx] = Whh[((size_t)d*512+gate)*128 + k];
  } else if (b < IB_Z+IB_C+IB_D+IB_E){
    int gid = (b-IB_Z-IB_C-IB_D)*4 + (tid>>6);
    int lane = tid & 63;
    if (gid < NH*HID){
      int h = gid/HID, c = gid%HID;
      const float* W = P.We_gat + (size_t)(h*HID+c)*OUTD;
      const float* a = P.a_e + h*OUTD;
      float acc = 0.f;
      for (int o=lane;o<OUTD;o+=64) acc += W[o]*a[o];
      for (int off=32;off>0;off>>=1) acc += __shfl_down(acc,off);
      if (lane==0) gwe_ae()[gid] = acc;
    } else if (gid < NH*HID+CAT){
      int c = gid - NH*HID;
      const float* W = P.We_out + (size_t)c*OUTD;
      float acc = 0.f;
      for (int o=lane;o<OUTD;o+=64) acc += W[o]*P.ao_e[o];
      for (int off=32;off>0;off>>=1) acc += __shfl_down(acc,off);
      if (lane==0) gv_e()[c] = acc;
    }
  } else {
    int unit = (b-IB_Z-IB_C-IB_D-IB_E)*4 + (tid>>6);
    if (unit >= 2*N) return;
    int g = unit / N, n = unit % N, c = tid & 63;
    const float* feat = P.g[g].feat;
    float acc = 0.f;
    for (int k=0;k<HID;k++) acc += feat[n*HID+k]*P.W_h[k*HID+c];
    float v = eluf(acc);
    float* f = gf(g);
    f[OH0 + n*HID + c] = v;
    float r = v*P.g1_w[c];
    for (int off=32;off>0;off>>=1) r += __shfl_down(r,off);
    if (c==0) f[ORAW1+n] = r;
  }
}

// ---- Wh[h] = h0 @ W_gat[h] + fused asn/adn; y==NH slice does gpool1 output ----
__global__ void k_Wh(Params P){
  int n = blockIdx.x, h = blockIdx.y, g = blockIdx.z, o = threadIdx.x;
  float* f = gf(g);
  if (h == NH){
    if (n != 0) return;
    __shared__ float att[N];
    __shared__ float sb[128];
    for (int j = o; j < N; j += 128) att[j] = sigmf(f[ORAW1+j] + P.g1_b[0]);
    __syncthreads();
    float m = -3e38f;
    for (int j = o; j < N; j += 128) m = fmaxf(m, att[j]);
    sb[o] = m; __syncthreads();
    for (int s=64;s>0;s>>=1){ if (o<s) sb[o]=fmaxf(sb[o],sb[o+s]); __syncthreads(); }
    m = sb[0]; __syncthreads();
    float ss = 0.f;
    for (int j = o; j < N; j += 128){ float e = expf(att[j]-m); ss += e; }
    sb[o] = ss; __syncthreads();
    for (int s=64;s>0;s>>=1){ if (o<s) sb[o]+=sb[o+s]; __syncthreads(); }
    float inv = 1.f/sb[0]; __syncthreads();
    for (int j = o; j < N; j += 128) att[j] = expf(att[j]-m)*inv;
    __syncthreads();
    if (o < HID){
      float acc = 0.f;
      for (int j=0;j<N;j++) acc += att[j]*f[OH0 + j*HID + o];
      gxseq()[g*SEQD + o] = acc;
    }
    return;
  }
  __shared__ float hs[HID];
  __shared__ float sred[128], dred[128];
  if (o < HID) hs[o] = f[OH0 + n*HID + o];
  __syncthreads();
  const float* W = P.W_gat + (size_t)h*HID*OUTD + o;
  float acc = 0.f;
  for (int c=0;c<HID;c++) acc += hs[c]*W[(size_t)c*OUTD];
  f[OWH + ((size_t)h*N + n)*OUTD + o] = acc;
  sred[o] = acc*P.a_src[h*OUTD+o];
  dred[o] = acc*P.a_dst[h*OUTD+o];
  __syncthreads();
  for (int s=64;s>0;s>>=1){ if (o<s){ sred[o]+=sred[o+s]; dred[o]+=dred[o+s]; } __syncthreads(); }
  if (o==0){ f[OASN+h*N+n]=sred[0]; f[OADN+h*N+n]=dred[0]; }
}

// ---- GAT layer 1: 4 nodes/block ----
__global__ void k_att1(Params P){
  int nb = blockIdx.x, h = blockIdx.y, g = blockIdx.z, tid = threadIdx.x;
  int n0 = nb*4;
  __shared__ float z[4][N];
  __shared__ float red[128];
  __shared__ float sinv[4];
  float* f = gf(g);
  const float* adj = P.g[g].adj;
  const int* pidx = gpidx(g);
  const float* edoth = G_EDOTH + ((size_t)g*NH + h)*E;
  const float* adn = f + OADN + h*N;
  for (int i=0;i<4;i++){
    float asn = f[OASN + h*N + n0+i];
    for (int j = tid; j < N; j += 128){
      float a = adj[(n0+i)*N + j];
      float zz;
      if (a > 0.f){
        int p = pidx[(n0+i)*N + j];
        float ee = (p >= 0) ? edoth[p] : 0.f;
        zz = lreluf(asn + adn[j] + ee);
      } else zz = -1e9f;
      z[i][j] = zz;
    }
  }
  __syncthreads();
  for (int i=0;i<4;i++){
    float m = -3e38f;
    for (int j = tid; j < N; j += 128) m = fmaxf(m, z[i][j]);
    red[tid] = m; __syncthreads();
    for (int s=64;s>0;s>>=1){ if (tid<s) red[tid]=fmaxf(red[tid],red[tid+s]); __syncthreads(); }
    m = red[0]; __syncthreads();
    float ssum = 0.f;
    for (int j = tid; j < N; j += 128){ float e = expf(z[i][j]-m); z[i][j]=e; ssum += e; }
    red[tid] = ssum; __syncthreads();
    for (int s=64;s>0;s>>=1){ if (tid<s) red[tid]+=red[tid+s]; __syncthreads(); }
    if (tid==0) sinv[i] = 1.f/red[0];
    __syncthreads();
  }
  const float* wh = f + OWH + (size_t)h*N*OUTD;
  float a0=0.f,a1=0.f,a2=0.f,a3=0.f;
  for (int j=0;j<N;j++){
    float w = wh[(size_t)j*OUTD + tid];
    a0 += z[0][j]*w; a1 += z[1][j]*w; a2 += z[2][j]*w; a3 += z[3][j]*w;
  }
  f[OH1 + (size_t)(n0+0)*CAT + h*OUTD + tid] = eluf(a0*sinv[0]);
  f[OH1 + (size_t)(n0+1)*CAT + h*OUTD + tid] = eluf(a1*sinv[1]);
  f[OH1 + (size_t)(n0+2)*CAT + h*OUTD + tid] = eluf(a2*sinv[2]);
  f[OH1 + (size_t)(n0+3)*CAT + h*OUTD + tid] = eluf(a3*sinv[3]);
}

// ---- pool1 node dots + fused g2 raw gate dot ----
__global__ void k_xw1(Params P){
  int n = blockIdx.x, g = blockIdx.y, tid = threadIdx.x;
  __shared__ float s1b[256], s2b[256], s3b[256];
  float* f = gf(g);
  const float* x = f + OH1 + (size_t)n*CAT;
  float a1 = 0.f, a2 = 0.f, a3 = 0.f;
  for (int c = tid; c < CAT; c += 256){
    float xv = x[c];
    a1 += xv*P.ep1_w[c];
    a2 += xv*P.ep1_w[CAT+c];
    a3 += xv*P.g2_w[c];
  }
  s1b[tid]=a1; s2b[tid]=a2; s3b[tid]=a3; __syncthreads();
  for (int s=128;s>0;s>>=1){
    if (tid<s){ s1b[tid]+=s1b[tid+s]; s2b[tid]+=s2b[tid+s]; s3b[tid]+=s3b[tid+s]; }
    __syncthreads();
  }
  if (tid==0){ f[OXW1+n]=s1b[0]; f[OXW2+n]=s2b[0]; f[ORAW2+n]=s3b[0]; }
}

// ---------------- pool1 edge scores + segment sums ----------------
__global__ void k_s1(Params P){
  int e = blockIdx.x*256 + threadIdx.x, g = blockIdx.y;
  if (e >= E) return;
  float* f = gf(g);
  const int* ei = P.g[g].eidx;
  int s = ei[e], d = ei[E+e];
  float v = sigmf(f[OXW1+s] + f[OXW2+d] + f[OEW1+e] + P.ep1_b[0]);
  f[OS1+e] = v;
  atomicAdd(&f[OSS1+s], v);
  atomicAdd(&f[ODEG1+s], 1.f);
}

// ---------------- pairIdx: last edge wins ----------------
__global__ void k_pairs(Params P){
  int e = blockIdx.x*256 + threadIdx.x, g = blockIdx.y;
  if (e >= E) return;
  const int* ei = P.g[g].eidx;
  atomicMax(&gpidx(g)[ei[e]*N + ei[E+e]], e);
}

// ---- gpool output (pools 2/3): inline gate; column-tiled ----
__global__ void k_gpool_out(Params P, int xoff, int D, int odeg, int rawoff,
                            const float* b, int outoff){
  int cb = blockIdx.x, g = blockIdx.y, tid = threadIdx.x;
  __shared__ float att[N];
  __shared__ float sb[256];
  float* f = gf(g);
  for (int n = tid; n < N; n += 256){
    float sc = f[odeg+256+n]/(f[odeg+n]+1e-6f);
    att[n] = sigmf(f[rawoff+n]*sc + b[0]);
  }
  __syncthreads();
  float m = -3e38f;
  for (int n = tid; n < N; n += 256) m = fmaxf(m, att[n]);
  sb[tid] = m; __syncthreads();
  for (int s=128;s>0;s>>=1){ if (tid<s) sb[tid]=fmaxf(sb[tid],sb[tid+s]); __syncthreads(); }
  m = sb[0]; __syncthreads();
  float ss = 0.f;
  for (int n = tid; n < N; n += 256){ float e = expf(att[n]-m); ss += e; }
  sb[tid] = ss; __syncthreads();
  for (int s=128;s>0;s>>=1){ if (tid<s) sb[tid]+=sb[tid+s]; __syncthreads(); }
  float inv = 1.f/sb[0]; __syncthreads();
  for (int n = tid; n < N; n += 256){
    float sc = f[odeg+256+n]/(f[odeg+n]+1e-6f);
    att[n] = expf(att[n]-m)*inv*sc;
  }
  __syncthreads();
  int c = cb*256 + tid;
  if (c < D){
    const float* x = f + xoff;
    float acc = 0.f;
    for (int n=0;n<N;n++) acc += att[n]*x[(size_t)n*D + c];
    gxseq()[g*SEQD + outoff + c] = acc;
  }
}

// ---- Wh2 (N,2; 512 thr) + fused asad2 tail ----
__global__ void k_Wh2(Params P){
  int n = blockIdx.x, g = blockIdx.y, tid = threadIdx.x;
  int kq = tid >> 7, o = tid & 127;
  __shared__ float hrow[4][128];
  __shared__ float part[4][128];
  __shared__ float sr[128], dr[128];
  float* f = gf(g);
  const float* x = f + OH1 + (size_t)n*CAT;
  float acc = 0.f;
  for (int cc=0; cc<4; cc++){
    int c0 = kq*512 + cc*128;
    __syncthreads();
    hrow[kq][o] = x[c0 + o];
    __syncthreads();
    const float* W = P.W_out + (size_t)c0*OUTD + o;
    for (int j=0;j<128;j++) acc += hrow[kq][j]*W[(size_t)j*OUTD];
  }
  part[kq][o] = acc;
  __syncthreads();
  if (kq==0){
    float ns = f[OSS1+n]/(f[ODEG1+n]+1e-6f);
    float a = part[0][o]+part[1][o]+part[2][o]+part[3][o];
    float v = a*ns;
    f[OWH2 + (size_t)n*OUTD + o] = v;
    sr[o] = v*P.ao_src[o];
    dr[o] = v*P.ao_dst[o];
  }
  __syncthreads();
  for (int s=64;s>0;s>>=1){
    if (tid<s){ sr[tid]+=sr[tid+s]; dr[tid]+=dr[tid+s]; }
    __syncthreads();
  }
  if (tid==0){ f[OAS2+n]=sr[0]; f[OAD2+n]=dr[0]; }
}

// ---- GAT layer 2; fused xs2/xd2 + g3 raw gate dot ----
__global__ void k_att2(Params P){
  int n = blockIdx.x, g = blockIdx.y, tid = threadIdx.x;
  __shared__ float z[N];
  __shared__ float red[128];
  __shared__ float dred[128];
  __shared__ float gred[128];
  float* f = gf(g);
  const float* adj = P.g[g].adj;
  const int* pidx = gpidx(g);
  float asn = f[OAS2+n];
  const float* adn = f + OAD2;
  for (int j = tid; j < N; j += 128){
    float a = adj[n*N + j];
    float zz;
    if (a > 0.f){
      int p = pidx[n*N + j];
      float ee = (p >= 0) ? f[OEWV+p]*f[OS1+p] : 0.f;
      zz = lreluf(asn + adn[j] + ee);
    } else zz = -1e9f;
    z[j] = zz;
  }
  __syncthreads();
  float m = -3e38f;
  for (int j = tid; j < N; j += 128) m = fmaxf(m, z[j]);
  red[tid] = m; __syncthreads();
  for (int s=64;s>0;s>>=1){ if (tid<s) red[tid]=fmaxf(red[tid],red[tid+s]); __syncthreads(); }
  m = red[0]; __syncthreads();
  float ssum = 0.f;
  for (int j = tid; j < N; j += 128){ float e = expf(z[j]-m); z[j]=e; ssum += e; }
  red[tid] = ssum; __syncthreads();
  for (int s=64;s>0;s>>=1){ if (tid<s) red[tid]+=red[tid+s]; __syncthreads(); }
  float inv = 1.f/red[0]; __syncthreads();
  const float* wh = f + OWH2;
  float acc = 0.f;
  for (int j=0;j<N;j++){
    float w = z[j];
    if (w != 0.f) acc += w * wh[(size_t)j*OUTD + tid];
  }
  float v = acc*inv;
  f[OH2B + (size_t)n*OUTD + tid] = v;
  red[tid]  = v*P.ep2_w[tid];
  dred[tid] = v*P.ep2_w[OUTD+tid];
  gred[tid] = v*P.g3_w[tid];
  __syncthreads();
  for (int s=64;s>0;s>>=1){
    if (tid<s){ red[tid]+=red[tid+s]; dred[tid]+=dred[tid+s]; gred[tid]+=gred[tid+s]; }
    __syncthreads();
  }
  if (tid==0){ f[OXS2+n]=red[0]; f[OXD2+n]=dred[0]; f[ORAW3+n]=gred[0]; }
}

// ---- e2 partial: register-tiled 4x4, fused ew1/ewv + EDOTH ----
constexpr int TE2 = 16;
__global__ __launch_bounds__(128, 2) void k_e2p(Params P){
  int e0 = blockIdx.x*TE2, h = blockIdx.y, g = blockIdx.z, tid = threadIdx.x;
  int cg = tid & 31, eg = tid >> 5;
  int c4 = cg*4, e4 = eg*4;
  __shared__ float es_t[HID][TE2+1];
  __shared__ float tcol_t[OUTD][TE2];
  const float* __restrict__ ea = P.g[g].eattr + (size_t)e0*HID;
  for (int i = tid; i < TE2*HID; i += 128) es_t[i & 63][i >> 6] = ea[i];
  __syncthreads();
  const float* __restrict__ W1 = P.We_gat + (size_t)h*HID*OUTD;
  const float* __restrict__ weae = gwe_ae() + h*HID;
  float t[4][4];
  float ed[4] = {0.f,0.f,0.f,0.f};
  #pragma unroll
  for (int i=0;i<4;i++){ t[i][0]=0.f; t[i][1]=0.f; t[i][2]=0.f; t[i][3]=0.f; }
  for (int c=0;c<HID;c++){
    float ev0 = es_t[c][e4+0], ev1 = es_t[c][e4+1], ev2 = es_t[c][e4+2], ev3 = es_t[c][e4+3];
    float4 w  = *(const float4*)&W1[(size_t)c*OUTD + c4];
    t[0][0]+=ev0*w.x; t[0][1]+=ev0*w.y; t[0][2]+=ev0*w.z; t[0][3]+=ev0*w.w;
    t[1][0]+=ev1*w.x; t[1][1]+=ev1*w.y; t[1][2]+=ev1*w.z; t[1][3]+=ev1*w.w;
    t[2][0]+=ev2*w.x; t[2][1]+=ev2*w.y; t[2][2]+=ev2*w.z; t[2][3]+=ev2*w.w;
    t[3][0]+=ev3*w.x; t[3][1]+=ev3*w.y; t[3][2]+=ev3*w.z; t[3][3]+=ev3*w.w;
    float wc = weae[c];
    ed[0]+=ev0*wc; ed[1]+=ev1*wc; ed[2]+=ev2*wc; ed[3]+=ev3*wc;
  }
  if (cg==0){
    float* eo = G_EDOTH + ((size_t)g*NH+h)*E + e0 + e4;
    eo[0]=ed[0]; eo[1]=ed[1]; eo[2]=ed[2]; eo[3]=ed[3];
  }
  #pragma unroll
  for (int i=0;i<4;i++){
    t[i][0]=eluf(t[i][0]); t[i][1]=eluf(t[i][1]); t[i][2]=eluf(t[i][2]); t[i][3]=eluf(t[i][3]);
  }
  {
    float4 w1 = *(const float4*)&P.ep1_w[2*CAT + h*OUTD + c4];
    float4 wv = *(const float4*)&gv_e()[h*OUTD + c4];
    #pragma unroll
    for (int i=0;i<4;i++){
      float a1 = t[i][0]*w1.x + t[i][1]*w1.y + t[i][2]*w1.z + t[i][3]*w1.w;
      float a2 = t[i][0]*wv.x + t[i][1]*wv.y + t[i][2]*wv.z + t[i][3]*wv.w;
      for (int off=16;off>0;off>>=1){
        a1 += __shfl_down(a1,off,32);
        a2 += __shfl_down(a2,off,32);
      }
      if (cg==0){
        atomicAdd(&gf(g)[OEW1 + e0+e4+i], a1);
        atomicAdd(&gf(g)[OEWV + e0+e4+i], a2);
      }
    }
  }
  #pragma unroll
  for (int j=0;j<4;j++){
    int o = c4 + j;
    int slot = (eg + (o>>2)) & 3;
    float4 v; v.x=t[0][j]; v.y=t[1][j]; v.z=t[2][j]; v.w=t[3][j];
    *(float4*)&tcol_t[o][4*slot] = v;
  }
  __syncthreads();
  const float* __restrict__ W2 = P.We_out + (size_t)h*OUTD*OUTD;
  float acc[4][4];
  #pragma unroll
  for (int i=0;i<4;i++){ acc[i][0]=0.f; acc[i][1]=0.f; acc[i][2]=0.f; acc[i][3]=0.f; }
  #pragma unroll 4
  for (int o=0;o<OUTD;o++){
    int slot = (eg + (o>>2)) & 3;
    float4 tv = *(const float4*)&tcol_t[o][4*slot];
    float4 w  = *(const float4*)&W2[(size_t)o*OUTD + c4];
    acc[0][0]+=tv.x*w.x; acc[0][1]+=tv.x*w.y; acc[0][2]+=tv.x*w.z; acc[0][3]+=tv.x*w.w;
    acc[1][0]+=tv.y*w.x; acc[1][1]+=tv.y*w.y; acc[1][2]+=tv.y*w.z; acc[1][3]+=tv.y*w.w;
    acc[2][0]+=tv.z*w.x; acc[2][1]+=tv.z*w.y; acc[2][2]+=tv.z*w.z; acc[2][3]+=tv.z*w.w;
    acc[3][0]+=tv.w*w.x; acc[3][1]+=tv.w*w.y; acc[3][2]+=tv.w*w.z; acc[3][3]+=tv.w*w.w;
  }
  float* dst = G_E2PART + (((size_t)h*2 + g)*E + e0)*OUTD;
  #pragma unroll
  for (int i=0;i<4;i++){
    float4 v; v.x=acc[i][0]; v.y=acc[i][1]; v.z=acc[i][2]; v.w=acc[i][3];
    *(float4*)&dst[(size_t)(e4+i)*OUTD + c4] = v;
  }
}

// ---- finish: sum head-partials, elu, dot ep2_w; fused s2 scoring + segment sums ----
__global__ void k_ew2fin(Params P){
  int e0 = blockIdx.x*TE2, g = blockIdx.y, tid = threadIdx.x;
  __shared__ float lred[2][TE2];
  float* f = gf(g);
  float w2 = P.ep2_w[2*OUTD + tid];
  int lane = tid & 63, wvi = tid >> 6;
  for (int e=0;e<TE2;e++){
    const float* src = G_E2PART + ((size_t)g*E + e0 + e)*OUTD + tid;
    float a = 0.f;
    for (int h=0;h<NH;h++) a += src[(size_t)h*2*E*OUTD];
    float v = eluf(f[OS1+e0+e]*a) * w2;
    for (int off=32;off>0;off>>=1) v += __shfl_down(v,off);
    if (lane==0) lred[wvi][e]=v;
  }
  __syncthreads();
  if (tid < TE2){
    int e = e0 + tid;
    float ew2 = lred[0][tid]+lred[1][tid];
    const int* ei = P.g[g].eidx;
    int s = ei[e], d = ei[E+e];
    float v = sigmf(f[OXS2+s] + f[OXD2+d] + ew2 + P.ep2_b[0]);
    atomicAdd(&f[OSS2+s], v);
    atomicAdd(&f[ODEG2+s], 1.f);
  }
}

// ---- LSTM input projection ----
__global__ void k_lstm_xg(Params P, int layer){
  int gid = blockIdx.x*4 + (threadIdx.x>>6);
  int lane = threadIdx.x & 63;
  int t = gid >> 10;
  int rem = gid & 1023;
  int d = rem >> 9;
  int gate = rem & 511;
  const float* Wih = layer ? P.Wih1 : P.Wih0;
  const float* bb  = layer ? P.b1   : P.b0;
  const float* xin = layer ? gy0()  : gxseq();
  int Din = layer ? 256 : SEQD;
  const float* x = xin + t*Din;
  const float* Wr = Wih + ((size_t)d*512 + gate)*Din;
  float acc = 0.f;
  for (int k=lane; k<Din; k+=64) acc += x[k]*Wr[k];
  for (int off=32; off>0; off>>=1) acc += __shfl_down(acc, off);
  if (lane==0) gxg()[(t*2 + d)*512 + gate] = acc + bb[d*512 + gate];
}

// ---- LSTM recurrence: coalesced via transposed Whh ----
__global__ void k_lstm_rec(Params P, int layer){
  int d = blockIdx.x, tid = threadIdx.x;
  float* yout = layer ? gy1() : gy0();
  const float* T = G_WHHT + (size_t)(layer*2 + d)*128*512;
  __shared__ float h[128], c[128], gbuf[512];
  if (tid < 128){ h[tid]=0.f; c[tid]=0.f; }
  __syncthreads();
  for (int s=0;s<2;s++){
    int t = (d==0) ? s : 1-s;
    float acc = gxg()[(t*2 + d)*512 + tid];
    for (int k=0;k<128;k++) acc += h[k]*T[(size_t)k*512 + tid];
    gbuf[tid] = acc;
    __syncthreads();
    if (tid < 128){
      float ii = sigmf(gbuf[tid]);
      float ff = sigmf(gbuf[128+tid]);
      float gg = tanhf(gbuf[256+tid]);
      float oo = sigmf(gbuf[384+tid]);
      float cn = ff*c[tid] + ii*gg;
      c[tid] = cn;
      float hn = oo*tanhf(cn);
      h[tid] = hn;
      yout[t*256 + d*128 + tid] = hn;
    }
    __syncthreads();
  }
}

// ---------------- final FC + softmax ----------------
__global__ void k_final(Params P){
  int tid = threadIdx.x;
  __shared__ float sb[256], sb2[256];
  const float* x = gy1() + 256;
  sb[tid]  = x[tid]*P.fc_w[tid*2+0];
  sb2[tid] = x[tid]*P.fc_w[tid*2+1];
  __syncthreads();
  for (int s=128;s>0;s>>=1){ if (tid<s){ sb[tid]+=sb[tid+s]; sb2[tid]+=sb2[tid+s]; } __syncthreads(); }
  if (tid==0){
    float l0 = sb[0] + P.fc_b[0];
    float l1 = sb2[0] + P.fc_b[1];
    float m = fmaxf(l0,l1);
    float e0 = expf(l0-m), e1 = expf(l1-m), inv = 1.f/(e0+e1);
    P.out[0] = e0*inv;
    P.out[1] = e1*inv;
  }
}

extern "C" void kernel_launch(void* const* d_in, const int* in_sizes, int n_in,
                              void* d_out, int out_size, void* d_ws, size_t ws_size,
                              hipStream_t stream){
  Params P;
  for (int g=0; g<2; ++g){
    int b = g*5;
    P.g[g].feat  = (const float*)d_in[b+0];
    P.g[g].eidx  = (const int*)d_in[b+1];
    P.g[g].eattr = (const float*)d_in[b+2];
    P.g[g].adj   = (const float*)d_in[b+3];
    P.g[g].n2n   = (const float*)d_in[b+4];
  }
  P.W_h   = (const float*)d_in[10];
  P.W_gat = (const float*)d_in[11];
  P.a_src = (const float*)d_in[12];
  P.a_dst = (const float*)d_in[13];
  P.a_e   = (const float*)d_in[14];
  P.We_gat= (const float*)d_in[15];
  P.W_out = (const float*)d_in[16];
  P.ao_src= (const float*)d_in[17];
  P.ao_dst= (const float*)d_in[18];
  P.ao_e  = (const float*)d_in[19];
  P.We_out= (const float*)d_in[20];
  P.ep1_w = (const float*)d_in[21];
  P.ep1_b = (const float*)d_in[22];
  P.ep2_w = (const float*)d_in[23];
  P.ep2_b = (const float*)d_in[24];
  P.g1_w  = (const float*)d_in[25];
  P.g1_b  = (const float*)d_in[26];
  P.g2_w  = (const float*)d_in[27];
  P.g2_b  = (const float*)d_in[28];
  P.g3_w  = (const float*)d_in[29];
  P.g3_b  = (const float*)d_in[30];
  P.Wih0  = (const float*)d_in[31];
  P.Whh0  = (const float*)d_in[32];
  P.b0    = (const float*)d_in[33];
  P.Wih1  = (const float*)d_in[34];
  P.Whh1  = (const float*)d_in[35];
  P.b1    = (const float*)d_in[36];
  P.fc_w  = (const float*)d_in[37];
  P.fc_b  = (const float*)d_in[38];
  P.out   = (float*)d_out;

  // ---- graph stages (17 dispatches) ----
  k_init <<<dim3(IB_Z+IB_C+IB_D+IB_E+IB_H), 256, 0, stream>>>(P);
  k_pairs<<<dim3((E+255)/256,2), 256, 0, stream>>>(P);
  k_e2p  <<<dim3(E/TE2,NH,2),128, 0, stream>>>(P);
  k_Wh   <<<dim3(N,NH+1,2), 128, 0, stream>>>(P);   // +gpool1 slice
  k_att1 <<<dim3(N/4,NH,2),128, 0, stream>>>(P);
  k_xw1  <<<dim3(N,2),    256, 0, stream>>>(P);
  k_s1   <<<dim3((E+255)/256,2), 256, 0, stream>>>(P);
  k_gpool_out<<<dim3(8,2), 256, 0, stream>>>(P, OH1, CAT, ODEG1, ORAW2, P.g2_b, HID);
  k_Wh2  <<<dim3(N,2),    512, 0, stream>>>(P);
  k_att2 <<<dim3(N,2),    128, 0, stream>>>(P);
  k_ew2fin<<<dim3(E/TE2,2),128, 0, stream>>>(P);    // +s2
  k_gpool_out<<<dim3(1,2), 256, 0, stream>>>(P, OH2B, OUTD, ODEG2, ORAW3, P.g3_b, HID+CAT);

  // ---- LSTM stack + classifier ----
  k_lstm_xg <<<dim3(512), 256, 0, stream>>>(P, 0);
  k_lstm_rec<<<dim3(2),   512, 0, stream>>>(P, 0);
  k_lstm_xg <<<dim3(512), 256, 0, stream>>>(P, 1);   // FIX: was dim3(2) — only 8/2048 dots computed
  k_lstm_rec<<<dim3(2),   512, 0, stream>>>(P, 1);
  k_final<<<dim3(1), 256, 0, stream>>>(P);
}

// Round 19
// 421.938 us; speedup vs baseline: 1.4849x; 1.0064x over previous
//
#include <hip/hip_runtime.h>
#include <math.h>

#define DI static __device__ __forceinline__

DI float eluf(float x){ return x > 0.f ? x : expm1f(x); }
DI float lreluf(float x){ return x > 0.f ? x : 0.2f*x; }
DI float sigmf(float x){ return 1.f/(1.f+expf(-x)); }

constexpr int N=200, E=3200, HID=64, NH=16, OUTD=128, CAT=2048, SEQD=2240;

// ---- per-graph f32 scratch offsets (in floats) ----
constexpr int OH0   = 0;
constexpr int OWH   = OH0 + N*HID;
constexpr int OASN  = OWH + NH*N*OUTD;
constexpr int OADN  = OASN + NH*N;
constexpr int OH1   = OADN + NH*N;
constexpr int OXW1  = OH1 + N*CAT;
constexpr int OXW2  = OXW1 + 256;
constexpr int OEW1  = OXW2 + 256;
constexpr int OS1   = OEW1 + E;
constexpr int ODEG1 = OS1 + E;
constexpr int OSS1  = ODEG1 + 256;   // = ODEG1+256 (inline ns relies on this)
constexpr int ORAW1 = OSS1 + 256;
constexpr int OWH2  = ORAW1 + 256;
constexpr int OAS2  = OWH2 + N*OUTD;
constexpr int OAD2  = OAS2 + 256;
constexpr int OEWV  = OAD2 + 256;
constexpr int OH2B  = OEWV + E;
constexpr int OXS2  = OH2B + N*OUTD;
constexpr int OXD2  = OXS2 + 256;
constexpr int ODEG2 = OXD2 + 256;
constexpr int OSS2  = ODEG2 + 256;   // = ODEG2+256
constexpr int ORAW2 = OSS2 + 256;
constexpr int ORAW3 = ORAW2 + 256;
constexpr int PGF   = ORAW3 + 256;
constexpr int GLOBF = 10624;
constexpr int TOTF  = GLOBF + 2*PGF;

// ---- static device scratch ----
__device__ float G_F[TOTF];
__device__ float G_E2PART[(size_t)NH*2*E*OUTD];   // used as [NH/2][2][E][OUTD]
__device__ float G_EDOTH[2*NH*E];
__device__ float G_WHHT[2*2*128*512];
__device__ int   G_PIDX[2*N*N];

DI float* gf(int g){ return G_F + GLOBF + (size_t)g*PGF; }
DI float* gwe_ae(){ return G_F; }
DI float* gv_e(){ return G_F + 1024; }
DI float* gy0(){ return G_F + 3072; }
DI float* gy1(){ return G_F + 3584; }
DI float* gxseq(){ return G_F + 4096; }
DI float* gxg(){ return G_F + 8576; }
DI int*   gpidx(int g){ return G_PIDX + g*N*N; }

struct GraphIn {
  const float *feat, *eattr, *adj, *n2n;
  const int   *eidx;
};

struct Params {
  GraphIn g[2];
  const float *W_h, *W_gat, *a_src, *a_dst, *a_e, *We_gat;
  const float *W_out, *ao_src, *ao_dst, *ao_e, *We_out;
  const float *ep1_w, *ep1_b, *ep2_w, *ep2_b;
  const float *g1_w, *g1_b, *g2_w, *g2_b, *g3_w, *g3_b;
  const float *Wih0, *Whh0, *b0, *Wih1, *Whh1, *b1, *fc_w, *fc_b;
  float *out;
};

// ---- fused init: zero atomic targets, pidx=-1, Whh transpose, precontract, h0+g1dot ----
constexpr int ZPG  = 2*E + 1024;              // per-graph floats to zero
constexpr int IB_Z = (2*ZPG+255)/256;
constexpr int IB_C = (2*N*N+255)/256;
constexpr int IB_D = (2*2*512*128)/256;
constexpr int IB_E = (NH*HID+CAT+3)/4;
constexpr int IB_H = (2*N+3)/4;
__global__ void k_init(Params P){
  int b = blockIdx.x, tid = threadIdx.x;
  if (b < IB_Z){
    int i = b*256 + tid;
    if (i < 2*ZPG){
      int g = i/ZPG, r = i%ZPG;
      int addr = r<E ? OEW1+r : (r<2*E ? OEWV+(r-E) :
                 (r<2*E+512 ? ODEG1+(r-2*E) : ODEG2+(r-2*E-512)));
      gf(g)[addr] = 0.f;
    }
  } else if (b < IB_Z+IB_C){
    int i = (b-IB_Z)*256 + tid; if (i < 2*N*N) G_PIDX[i] = -1;
  } else if (b < IB_Z+IB_C+IB_D){
    int idx = (b-IB_Z-IB_C)*256 + tid;
    int l = idx >> 17;
    int r = idx & 131071;
    int d = r >> 16;
    int r2 = r & 65535;
    int gate = r2 & 511;
    int k = r2 >> 9;
    const float* Whh = l ? P.Whh1 : P.Whh0;
    G_WHHT[idx] = Whh[((size_t)d*512+gate)*128 + k];
  } else if (b < IB_Z+IB_C+IB_D+IB_E){
    int gid = (b-IB_Z-IB_C-IB_D)*4 + (tid>>6);
    int lane = tid & 63;
    if (gid < NH*HID){
      int h = gid/HID, c = gid%HID;
      const float* W = P.We_gat + (size_t)(h*HID+c)*OUTD;
      const float* a = P.a_e + h*OUTD;
      float acc = 0.f;
      for (int o=lane;o<OUTD;o+=64) acc += W[o]*a[o];
      for (int off=32;off>0;off>>=1) acc += __shfl_down(acc,off);
      if (lane==0) gwe_ae()[gid] = acc;
    } else if (gid < NH*HID+CAT){
      int c = gid - NH*HID;
      const float* W = P.We_out + (size_t)c*OUTD;
      float acc = 0.f;
      for (int o=lane;o<OUTD;o+=64) acc += W[o]*P.ao_e[o];
      for (int off=32;off>0;off>>=1) acc += __shfl_down(acc,off);
      if (lane==0) gv_e()[c] = acc;
    }
  } else {
    int unit = (b-IB_Z-IB_C-IB_D-IB_E)*4 + (tid>>6);
    if (unit >= 2*N) return;
    int g = unit / N, n = unit % N, c = tid & 63;
    const float* feat = P.g[g].feat;
    float acc = 0.f;
    for (int k=0;k<HID;k++) acc += feat[n*HID+k]*P.W_h[k*HID+c];
    float v = eluf(acc);
    float* f = gf(g);
    f[OH0 + n*HID + c] = v;
    float r = v*P.g1_w[c];
    for (int off=32;off>0;off>>=1) r += __shfl_down(r,off);
    if (c==0) f[ORAW1+n] = r;
  }
}

// ---- Wh[h] = h0 @ W_gat[h] + fused asn/adn; y==NH slice does gpool1 output ----
__global__ void k_Wh(Params P){
  int n = blockIdx.x, h = blockIdx.y, g = blockIdx.z, o = threadIdx.x;
  float* f = gf(g);
  if (h == NH){
    if (n != 0) return;
    __shared__ float att[N];
    __shared__ float sb[128];
    for (int j = o; j < N; j += 128) att[j] = sigmf(f[ORAW1+j] + P.g1_b[0]);
    __syncthreads();
    float m = -3e38f;
    for (int j = o; j < N; j += 128) m = fmaxf(m, att[j]);
    sb[o] = m; __syncthreads();
    for (int s=64;s>0;s>>=1){ if (o<s) sb[o]=fmaxf(sb[o],sb[o+s]); __syncthreads(); }
    m = sb[0]; __syncthreads();
    float ss = 0.f;
    for (int j = o; j < N; j += 128){ float e = expf(att[j]-m); ss += e; }
    sb[o] = ss; __syncthreads();
    for (int s=64;s>0;s>>=1){ if (o<s) sb[o]+=sb[o+s]; __syncthreads(); }
    float inv = 1.f/sb[0]; __syncthreads();
    for (int j = o; j < N; j += 128) att[j] = expf(att[j]-m)*inv;
    __syncthreads();
    if (o < HID){
      float acc = 0.f;
      for (int j=0;j<N;j++) acc += att[j]*f[OH0 + j*HID + o];
      gxseq()[g*SEQD + o] = acc;
    }
    return;
  }
  __shared__ float hs[HID];
  __shared__ float sred[128], dred[128];
  if (o < HID) hs[o] = f[OH0 + n*HID + o];
  __syncthreads();
  const float* W = P.W_gat + (size_t)h*HID*OUTD + o;
  float acc = 0.f;
  for (int c=0;c<HID;c++) acc += hs[c]*W[(size_t)c*OUTD];
  f[OWH + ((size_t)h*N + n)*OUTD + o] = acc;
  sred[o] = acc*P.a_src[h*OUTD+o];
  dred[o] = acc*P.a_dst[h*OUTD+o];
  __syncthreads();
  for (int s=64;s>0;s>>=1){ if (o<s){ sred[o]+=sred[o+s]; dred[o]+=dred[o+s]; } __syncthreads(); }
  if (o==0){ f[OASN+h*N+n]=sred[0]; f[OADN+h*N+n]=dred[0]; }
}

// ---- GAT layer 1: 4 nodes/block ----
__global__ void k_att1(Params P){
  int nb = blockIdx.x, h = blockIdx.y, g = blockIdx.z, tid = threadIdx.x;
  int n0 = nb*4;
  __shared__ float z[4][N];
  __shared__ float red[128];
  __shared__ float sinv[4];
  float* f = gf(g);
  const float* adj = P.g[g].adj;
  const int* pidx = gpidx(g);
  const float* edoth = G_EDOTH + ((size_t)g*NH + h)*E;
  const float* adn = f + OADN + h*N;
  for (int i=0;i<4;i++){
    float asn = f[OASN + h*N + n0+i];
    for (int j = tid; j < N; j += 128){
      float a = adj[(n0+i)*N + j];
      float zz;
      if (a > 0.f){
        int p = pidx[(n0+i)*N + j];
        float ee = (p >= 0) ? edoth[p] : 0.f;
        zz = lreluf(asn + adn[j] + ee);
      } else zz = -1e9f;
      z[i][j] = zz;
    }
  }
  __syncthreads();
  for (int i=0;i<4;i++){
    float m = -3e38f;
    for (int j = tid; j < N; j += 128) m = fmaxf(m, z[i][j]);
    red[tid] = m; __syncthreads();
    for (int s=64;s>0;s>>=1){ if (tid<s) red[tid]=fmaxf(red[tid],red[tid+s]); __syncthreads(); }
    m = red[0]; __syncthreads();
    float ssum = 0.f;
    for (int j = tid; j < N; j += 128){ float e = expf(z[i][j]-m); z[i][j]=e; ssum += e; }
    red[tid] = ssum; __syncthreads();
    for (int s=64;s>0;s>>=1){ if (tid<s) red[tid]+=red[tid+s]; __syncthreads(); }
    if (tid==0) sinv[i] = 1.f/red[0];
    __syncthreads();
  }
  const float* wh = f + OWH + (size_t)h*N*OUTD;
  float a0=0.f,a1=0.f,a2=0.f,a3=0.f;
  for (int j=0;j<N;j++){
    float w = wh[(size_t)j*OUTD + tid];
    a0 += z[0][j]*w; a1 += z[1][j]*w; a2 += z[2][j]*w; a3 += z[3][j]*w;
  }
  f[OH1 + (size_t)(n0+0)*CAT + h*OUTD + tid] = eluf(a0*sinv[0]);
  f[OH1 + (size_t)(n0+1)*CAT + h*OUTD + tid] = eluf(a1*sinv[1]);
  f[OH1 + (size_t)(n0+2)*CAT + h*OUTD + tid] = eluf(a2*sinv[2]);
  f[OH1 + (size_t)(n0+3)*CAT + h*OUTD + tid] = eluf(a3*sinv[3]);
}

// ---- pool1 node dots + fused g2 raw gate dot ----
__global__ void k_xw1(Params P){
  int n = blockIdx.x, g = blockIdx.y, tid = threadIdx.x;
  __shared__ float s1b[256], s2b[256], s3b[256];
  float* f = gf(g);
  const float* x = f + OH1 + (size_t)n*CAT;
  float a1 = 0.f, a2 = 0.f, a3 = 0.f;
  for (int c = tid; c < CAT; c += 256){
    float xv = x[c];
    a1 += xv*P.ep1_w[c];
    a2 += xv*P.ep1_w[CAT+c];
    a3 += xv*P.g2_w[c];
  }
  s1b[tid]=a1; s2b[tid]=a2; s3b[tid]=a3; __syncthreads();
  for (int s=128;s>0;s>>=1){
    if (tid<s){ s1b[tid]+=s1b[tid+s]; s2b[tid]+=s2b[tid+s]; s3b[tid]+=s3b[tid+s]; }
    __syncthreads();
  }
  if (tid==0){ f[OXW1+n]=s1b[0]; f[OXW2+n]=s2b[0]; f[ORAW2+n]=s3b[0]; }
}

// ---------------- pool1 edge scores + segment sums ----------------
__global__ void k_s1(Params P){
  int e = blockIdx.x*256 + threadIdx.x, g = blockIdx.y;
  if (e >= E) return;
  float* f = gf(g);
  const int* ei = P.g[g].eidx;
  int s = ei[e], d = ei[E+e];
  float v = sigmf(f[OXW1+s] + f[OXW2+d] + f[OEW1+e] + P.ep1_b[0]);
  f[OS1+e] = v;
  atomicAdd(&f[OSS1+s], v);
  atomicAdd(&f[ODEG1+s], 1.f);
}

// ---------------- pairIdx: last edge wins ----------------
__global__ void k_pairs(Params P){
  int e = blockIdx.x*256 + threadIdx.x, g = blockIdx.y;
  if (e >= E) return;
  const int* ei = P.g[g].eidx;
  atomicMax(&gpidx(g)[ei[e]*N + ei[E+e]], e);
}

// ---- gpool output (pools 2/3): inline gate; column-tiled ----
__global__ void k_gpool_out(Params P, int xoff, int D, int odeg, int rawoff,
                            const float* b, int outoff){
  int cb = blockIdx.x, g = blockIdx.y, tid = threadIdx.x;
  __shared__ float att[N];
  __shared__ float sb[256];
  float* f = gf(g);
  for (int n = tid; n < N; n += 256){
    float sc = f[odeg+256+n]/(f[odeg+n]+1e-6f);
    att[n] = sigmf(f[rawoff+n]*sc + b[0]);
  }
  __syncthreads();
  float m = -3e38f;
  for (int n = tid; n < N; n += 256) m = fmaxf(m, att[n]);
  sb[tid] = m; __syncthreads();
  for (int s=128;s>0;s>>=1){ if (tid<s) sb[tid]=fmaxf(sb[tid],sb[tid+s]); __syncthreads(); }
  m = sb[0]; __syncthreads();
  float ss = 0.f;
  for (int n = tid; n < N; n += 256){ float e = expf(att[n]-m); ss += e; }
  sb[tid] = ss; __syncthreads();
  for (int s=128;s>0;s>>=1){ if (tid<s) sb[tid]+=sb[tid+s]; __syncthreads(); }
  float inv = 1.f/sb[0]; __syncthreads();
  for (int n = tid; n < N; n += 256){
    float sc = f[odeg+256+n]/(f[odeg+n]+1e-6f);
    att[n] = expf(att[n]-m)*inv*sc;
  }
  __syncthreads();
  int c = cb*256 + tid;
  if (c < D){
    const float* x = f + xoff;
    float acc = 0.f;
    for (int n=0;n<N;n++) acc += att[n]*x[(size_t)n*D + c];
    gxseq()[g*SEQD + outoff + c] = acc;
  }
}

// ---- Wh2 (N,2; 512 thr) + fused asad2 tail ----
__global__ void k_Wh2(Params P){
  int n = blockIdx.x, g = blockIdx.y, tid = threadIdx.x;
  int kq = tid >> 7, o = tid & 127;
  __shared__ float hrow[4][128];
  __shared__ float part[4][128];
  __shared__ float sr[128], dr[128];
  float* f = gf(g);
  const float* x = f + OH1 + (size_t)n*CAT;
  float acc = 0.f;
  for (int cc=0; cc<4; cc++){
    int c0 = kq*512 + cc*128;
    __syncthreads();
    hrow[kq][o] = x[c0 + o];
    __syncthreads();
    const float* W = P.W_out + (size_t)c0*OUTD + o;
    for (int j=0;j<128;j++) acc += hrow[kq][j]*W[(size_t)j*OUTD];
  }
  part[kq][o] = acc;
  __syncthreads();
  if (kq==0){
    float ns = f[OSS1+n]/(f[ODEG1+n]+1e-6f);
    float a = part[0][o]+part[1][o]+part[2][o]+part[3][o];
    float v = a*ns;
    f[OWH2 + (size_t)n*OUTD + o] = v;
    sr[o] = v*P.ao_src[o];
    dr[o] = v*P.ao_dst[o];
  }
  __syncthreads();
  for (int s=64;s>0;s>>=1){
    if (tid<s){ sr[tid]+=sr[tid+s]; dr[tid]+=dr[tid+s]; }
    __syncthreads();
  }
  if (tid==0){ f[OAS2+n]=sr[0]; f[OAD2+n]=dr[0]; }
}

// ---- GAT layer 2; fused xs2/xd2 + g3 raw gate dot ----
__global__ void k_att2(Params P){
  int n = blockIdx.x, g = blockIdx.y, tid = threadIdx.x;
  __shared__ float z[N];
  __shared__ float red[128];
  __shared__ float dred[128];
  __shared__ float gred[128];
  float* f = gf(g);
  const float* adj = P.g[g].adj;
  const int* pidx = gpidx(g);
  float asn = f[OAS2+n];
  const float* adn = f + OAD2;
  for (int j = tid; j < N; j += 128){
    float a = adj[n*N + j];
    float zz;
    if (a > 0.f){
      int p = pidx[n*N + j];
      float ee = (p >= 0) ? f[OEWV+p]*f[OS1+p] : 0.f;
      zz = lreluf(asn + adn[j] + ee);
    } else zz = -1e9f;
    z[j] = zz;
  }
  __syncthreads();
  float m = -3e38f;
  for (int j = tid; j < N; j += 128) m = fmaxf(m, z[j]);
  red[tid] = m; __syncthreads();
  for (int s=64;s>0;s>>=1){ if (tid<s) red[tid]=fmaxf(red[tid],red[tid+s]); __syncthreads(); }
  m = red[0]; __syncthreads();
  float ssum = 0.f;
  for (int j = tid; j < N; j += 128){ float e = expf(z[j]-m); z[j]=e; ssum += e; }
  red[tid] = ssum; __syncthreads();
  for (int s=64;s>0;s>>=1){ if (tid<s) red[tid]+=red[tid+s]; __syncthreads(); }
  float inv = 1.f/red[0]; __syncthreads();
  const float* wh = f + OWH2;
  float acc = 0.f;
  for (int j=0;j<N;j++){
    float w = z[j];
    if (w != 0.f) acc += w * wh[(size_t)j*OUTD + tid];
  }
  float v = acc*inv;
  f[OH2B + (size_t)n*OUTD + tid] = v;
  red[tid]  = v*P.ep2_w[tid];
  dred[tid] = v*P.ep2_w[OUTD+tid];
  gred[tid] = v*P.g3_w[tid];
  __syncthreads();
  for (int s=64;s>0;s>>=1){
    if (tid<s){ red[tid]+=red[tid+s]; dred[tid]+=dred[tid+s]; gred[tid]+=gred[tid+s]; }
    __syncthreads();
  }
  if (tid==0){ f[OXS2+n]=red[0]; f[OXD2+n]=dred[0]; f[ORAW3+n]=gred[0]; }
}

// ---- e2 partial: register-tiled 4x4, 2 heads/block, fused ew1/ewv + EDOTH ----
constexpr int TE2 = 16;
__global__ __launch_bounds__(128, 2) void k_e2p(Params P){
  int e0 = blockIdx.x*TE2, hg = blockIdx.y, g = blockIdx.z, tid = threadIdx.x;
  int cg = tid & 31, eg = tid >> 5;
  int c4 = cg*4, e4 = eg*4;
  __shared__ float es_t[HID][TE2+1];
  __shared__ float tcol_t[2][OUTD][TE2];     // one per head in the pair
  const float* __restrict__ ea = P.g[g].eattr + (size_t)e0*HID;
  for (int i = tid; i < TE2*HID; i += 128) es_t[i & 63][i >> 6] = ea[i];
  __syncthreads();
  for (int hh=0; hh<2; ++hh){
    int h = hg*2 + hh;
    const float* __restrict__ W1 = P.We_gat + (size_t)h*HID*OUTD;
    const float* __restrict__ weae = gwe_ae() + h*HID;
    float t[4][4];
    float ed[4] = {0.f,0.f,0.f,0.f};
    #pragma unroll
    for (int i=0;i<4;i++){ t[i][0]=0.f; t[i][1]=0.f; t[i][2]=0.f; t[i][3]=0.f; }
    for (int c=0;c<HID;c++){
      float ev0 = es_t[c][e4+0], ev1 = es_t[c][e4+1], ev2 = es_t[c][e4+2], ev3 = es_t[c][e4+3];
      float4 w  = *(const float4*)&W1[(size_t)c*OUTD + c4];
      t[0][0]+=ev0*w.x; t[0][1]+=ev0*w.y; t[0][2]+=ev0*w.z; t[0][3]+=ev0*w.w;
      t[1][0]+=ev1*w.x; t[1][1]+=ev1*w.y; t[1][2]+=ev1*w.z; t[1][3]+=ev1*w.w;
      t[2][0]+=ev2*w.x; t[2][1]+=ev2*w.y; t[2][2]+=ev2*w.z; t[2][3]+=ev2*w.w;
      t[3][0]+=ev3*w.x; t[3][1]+=ev3*w.y; t[3][2]+=ev3*w.z; t[3][3]+=ev3*w.w;
      float wc = weae[c];
      ed[0]+=ev0*wc; ed[1]+=ev1*wc; ed[2]+=ev2*wc; ed[3]+=ev3*wc;
    }
    if (cg==0){
      float* eo = G_EDOTH + ((size_t)g*NH+h)*E + e0 + e4;
      eo[0]=ed[0]; eo[1]=ed[1]; eo[2]=ed[2]; eo[3]=ed[3];
    }
    #pragma unroll
    for (int i=0;i<4;i++){
      t[i][0]=eluf(t[i][0]); t[i][1]=eluf(t[i][1]); t[i][2]=eluf(t[i][2]); t[i][3]=eluf(t[i][3]);
    }
    {
      float4 w1 = *(const float4*)&P.ep1_w[2*CAT + h*OUTD + c4];
      float4 wv = *(const float4*)&gv_e()[h*OUTD + c4];
      #pragma unroll
      for (int i=0;i<4;i++){
        float a1 = t[i][0]*w1.x + t[i][1]*w1.y + t[i][2]*w1.z + t[i][3]*w1.w;
        float a2 = t[i][0]*wv.x + t[i][1]*wv.y + t[i][2]*wv.z + t[i][3]*wv.w;
        for (int off=16;off>0;off>>=1){
          a1 += __shfl_down(a1,off,32);
          a2 += __shfl_down(a2,off,32);
        }
        if (cg==0){
          atomicAdd(&gf(g)[OEW1 + e0+e4+i], a1);
          atomicAdd(&gf(g)[OEWV + e0+e4+i], a2);
        }
      }
    }
    #pragma unroll
    for (int j=0;j<4;j++){
      int o = c4 + j;
      int slot = (eg + (o>>2)) & 3;
      float4 v; v.x=t[0][j]; v.y=t[1][j]; v.z=t[2][j]; v.w=t[3][j];
      *(float4*)&tcol_t[hh][o][4*slot] = v;
    }
  }
  __syncthreads();
  float acc[4][4];
  #pragma unroll
  for (int i=0;i<4;i++){ acc[i][0]=0.f; acc[i][1]=0.f; acc[i][2]=0.f; acc[i][3]=0.f; }
  for (int hh=0; hh<2; ++hh){
    const float* __restrict__ W2 = P.We_out + (size_t)(hg*2+hh)*OUTD*OUTD;
    #pragma unroll 4
    for (int o=0;o<OUTD;o++){
      int slot = (eg + (o>>2)) & 3;
      float4 tv = *(const float4*)&tcol_t[hh][o][4*slot];
      float4 w  = *(const float4*)&W2[(size_t)o*OUTD + c4];
      acc[0][0]+=tv.x*w.x; acc[0][1]+=tv.x*w.y; acc[0][2]+=tv.x*w.z; acc[0][3]+=tv.x*w.w;
      acc[1][0]+=tv.y*w.x; acc[1][1]+=tv.y*w.y; acc[1][2]+=tv.y*w.z; acc[1][3]+=tv.y*w.w;
      acc[2][0]+=tv.z*w.x; acc[2][1]+=tv.z*w.y; acc[2][2]+=tv.z*w.z; acc[2][3]+=tv.z*w.w;
      acc[3][0]+=tv.w*w.x; acc[3][1]+=tv.w*w.y; acc[3][2]+=tv.w*w.z; acc[3][3]+=tv.w*w.w;
    }
  }
  float* dst = G_E2PART + (((size_t)hg*2 + g)*E + e0)*OUTD;
  #pragma unroll
  for (int i=0;i<4;i++){
    float4 v; v.x=acc[i][0]; v.y=acc[i][1]; v.z=acc[i][2]; v.w=acc[i][3];
    *(float4*)&dst[(size_t)(e4+i)*OUTD + c4] = v;
  }
}

// ---- finish: sum 8 head-pair partials, elu, dot ep2_w; fused s2 ----
__global__ void k_ew2fin(Params P){
  int e0 = blockIdx.x*TE2, g = blockIdx.y, tid = threadIdx.x;
  __shared__ float lred[2][TE2];
  float* f = gf(g);
  float w2 = P.ep2_w[2*OUTD + tid];
  int lane = tid & 63, wvi = tid >> 6;
  for (int e=0;e<TE2;e++){
    const float* src = G_E2PART + ((size_t)g*E + e0 + e)*OUTD + tid;
    float a = 0.f;
    for (int h=0;h<NH/2;h++) a += src[(size_t)h*2*E*OUTD];
    float v = eluf(f[OS1+e0+e]*a) * w2;
    for (int off=32;off>0;off>>=1) v += __shfl_down(v,off);
    if (lane==0) lred[wvi][e]=v;
  }
  __syncthreads();
  if (tid < TE2){
    int e = e0 + tid;
    float ew2 = lred[0][tid]+lred[1][tid];
    const int* ei = P.g[g].eidx;
    int s = ei[e], d = ei[E+e];
    float v = sigmf(f[OXS2+s] + f[OXD2+d] + ew2 + P.ep2_b[0]);
    atomicAdd(&f[OSS2+s], v);
    atomicAdd(&f[ODEG2+s], 1.f);
  }
}

// ---- LSTM input projection ----
__global__ void k_lstm_xg(Params P, int layer){
  int gid = blockIdx.x*4 + (threadIdx.x>>6);
  int lane = threadIdx.x & 63;
  int t = gid >> 10;
  int rem = gid & 1023;
  int d = rem >> 9;
  int gate = rem & 511;
  const float* Wih = layer ? P.Wih1 : P.Wih0;
  const float* bb  = layer ? P.b1   : P.b0;
  const float* xin = layer ? gy0()  : gxseq();
  int Din = layer ? 256 : SEQD;
  const float* x = xin + t*Din;
  const float* Wr = Wih + ((size_t)d*512 + gate)*Din;
  float acc = 0.f;
  for (int k=lane; k<Din; k+=64) acc += x[k]*Wr[k];
  for (int off=32; off>0; off>>=1) acc += __shfl_down(acc, off);
  if (lane==0) gxg()[(t*2 + d)*512 + gate] = acc + bb[d*512 + gate];
}

// ---- LSTM recurrence: coalesced via transposed Whh ----
__global__ void k_lstm_rec(Params P, int layer){
  int d = blockIdx.x, tid = threadIdx.x;
  float* yout = layer ? gy1() : gy0();
  const float* T = G_WHHT + (size_t)(layer*2 + d)*128*512;
  __shared__ float h[128], c[128], gbuf[512];
  if (tid < 128){ h[tid]=0.f; c[tid]=0.f; }
  __syncthreads();
  for (int s=0;s<2;s++){
    int t = (d==0) ? s : 1-s;
    float acc = gxg()[(t*2 + d)*512 + tid];
    for (int k=0;k<128;k++) acc += h[k]*T[(size_t)k*512 + tid];
    gbuf[tid] = acc;
    __syncthreads();
    if (tid < 128){
      float ii = sigmf(gbuf[tid]);
      float ff = sigmf(gbuf[128+tid]);
      float gg = tanhf(gbuf[256+tid]);
      float oo = sigmf(gbuf[384+tid]);
      float cn = ff*c[tid] + ii*gg;
      c[tid] = cn;
      float hn = oo*tanhf(cn);
      h[tid] = hn;
      yout[t*256 + d*128 + tid] = hn;
    }
    __syncthreads();
  }
}

// ---------------- final FC + softmax ----------------
__global__ void k_final(Params P){
  int tid = threadIdx.x;
  __shared__ float sb[256], sb2[256];
  const float* x = gy1() + 256;
  sb[tid]  = x[tid]*P.fc_w[tid*2+0];
  sb2[tid] = x[tid]*P.fc_w[tid*2+1];
  __syncthreads();
  for (int s=128;s>0;s>>=1){ if (tid<s){ sb[tid]+=sb[tid+s]; sb2[tid]+=sb2[tid+s]; } __syncthreads(); }
  if (tid==0){
    float l0 = sb[0] + P.fc_b[0];
    float l1 = sb2[0] + P.fc_b[1];
    float m = fmaxf(l0,l1);
    float e0 = expf(l0-m), e1 = expf(l1-m), inv = 1.f/(e0+e1);
    P.out[0] = e0*inv;
    P.out[1] = e1*inv;
  }
}

extern "C" void kernel_launch(void* const* d_in, const int* in_sizes, int n_in,
                              void* d_out, int out_size, void* d_ws, size_t ws_size,
                              hipStream_t stream){
  Params P;
  for (int g=0; g<2; ++g){
    int b = g*5;
    P.g[g].feat  = (const float*)d_in[b+0];
    P.g[g].eidx  = (const int*)d_in[b+1];
    P.g[g].eattr = (const float*)d_in[b+2];
    P.g[g].adj   = (const float*)d_in[b+3];
    P.g[g].n2n   = (const float*)d_in[b+4];
  }
  P.W_h   = (const float*)d_in[10];
  P.W_gat = (const float*)d_in[11];
  P.a_src = (const float*)d_in[12];
  P.a_dst = (const float*)d_in[13];
  P.a_e   = (const float*)d_in[14];
  P.We_gat= (const float*)d_in[15];
  P.W_out = (const float*)d_in[16];
  P.ao_src= (const float*)d_in[17];
  P.ao_dst= (const float*)d_in[18];
  P.ao_e  = (const float*)d_in[19];
  P.We_out= (const float*)d_in[20];
  P.ep1_w = (const float*)d_in[21];
  P.ep1_b = (const float*)d_in[22];
  P.ep2_w = (const float*)d_in[23];
  P.ep2_b = (const float*)d_in[24];
  P.g1_w  = (const float*)d_in[25];
  P.g1_b  = (const float*)d_in[26];
  P.g2_w  = (const float*)d_in[27];
  P.g2_b  = (const float*)d_in[28];
  P.g3_w  = (const float*)d_in[29];
  P.g3_b  = (const float*)d_in[30];
  P.Wih0  = (const float*)d_in[31];
  P.Whh0  = (const float*)d_in[32];
  P.b0    = (const float*)d_in[33];
  P.Wih1  = (const float*)d_in[34];
  P.Whh1  = (const float*)d_in[35];
  P.b1    = (const float*)d_in[36];
  P.fc_w  = (const float*)d_in[37];
  P.fc_b  = (const float*)d_in[38];
  P.out   = (float*)d_out;

  // ---- graph stages (17 dispatches) ----
  k_init <<<dim3(IB_Z+IB_C+IB_D+IB_E+IB_H), 256, 0, stream>>>(P);
  k_pairs<<<dim3((E+255)/256,2), 256, 0, stream>>>(P);
  k_e2p  <<<dim3(E/TE2,NH/2,2),128, 0, stream>>>(P);   // 2 heads/block
  k_Wh   <<<dim3(N,NH+1,2), 128, 0, stream>>>(P);      // +gpool1 slice
  k_att1 <<<dim3(N/4,NH,2),128, 0, stream>>>(P);
  k_xw1  <<<dim3(N,2),    256, 0, stream>>>(P);
  k_s1   <<<dim3((E+255)/256,2), 256, 0, stream>>>(P);
  k_gpool_out<<<dim3(8,2), 256, 0, stream>>>(P, OH1, CAT, ODEG1, ORAW2, P.g2_b, HID);
  k_Wh2  <<<dim3(N,2),    512, 0, stream>>>(P);
  k_att2 <<<dim3(N,2),    128, 0, stream>>>(P);
  k_ew2fin<<<dim3(E/TE2,2),128, 0, stream>>>(P);       // +s2
  k_gpool_out<<<dim3(1,2), 256, 0, stream>>>(P, OH2B, OUTD, ODEG2, ORAW3, P.g3_b, HID+CAT);

  // ---- LSTM stack + classifier ----
  k_lstm_xg <<<dim3(512), 256, 0, stream>>>(P, 0);
  k_lstm_rec<<<dim3(2),   512, 0, stream>>>(P, 0);
  k_lstm_xg <<<dim3(512), 256, 0, stream>>>(P, 1);
  k_lstm_rec<<<dim3(2),   512, 0, stream>>>(P, 1);
  k_final<<<dim3(1), 256, 0, stream>>>(P);
}